// Round 4
// baseline (281.340 us; speedup 1.0000x reference)
//
#include <hip/hip_runtime.h>
#include <hip/hip_bf16.h>

#define CDIM 128
#define EDIM 16
#define NEG_SLOPE 0.2f
#define PA_EPT 8

typedef __attribute__((ext_vector_type(8))) short bf16x8;
typedef __attribute__((ext_vector_type(4))) float f32x4;
typedef unsigned int uint;
typedef unsigned short ushort;

__device__ __forceinline__ ushort f2bf(float f) {
    uint u = __float_as_uint(f);
    return (ushort)((u + 0x7fffu + ((u >> 16) & 1u)) >> 16);
}
__device__ __forceinline__ uint packbf(float lo, float hi) {
    return ((uint)f2bf(hi) << 16) | (uint)f2bf(lo);
}
__device__ __forceinline__ float bflo(uint w) { return __uint_as_float(w << 16); }
__device__ __forceinline__ float bfhi(uint w) { return __uint_as_float(w & 0xffff0000u); }

__device__ __forceinline__ bool redtest(const void* red, int i, int notInt, int notFloat) {
    if (!notInt)        return ((const int*)red)[i] != 0;
    else if (!notFloat) return ((const float*)red)[i] != 0.f;
    else                return ((const unsigned char*)red)[i] != 0;
}

// ---------------- prep: dtype flags + in-degree histogram + octant histogram ----------------
__global__ __launch_bounds__(256) void prep_kernel(const uint* __restrict__ red, int nwords,
                                                   int* __restrict__ flags,
                                                   const int* __restrict__ dst, int* __restrict__ cnt,
                                                   int* __restrict__ octCnt, int E, int qN) {
    __shared__ int loct[8];
    int t = threadIdx.x;
    if (t < 8) loct[t] = 0;
    __syncthreads();
    int i = blockIdx.x * 256 + t;
    if (i < nwords) {
        uint w = red[i];
        bool isInt = (w <= 1u);
        bool isFloat = (w == 0u) || (w == 0x3f800000u);
        if (!isInt) atomicOr(&flags[0], 1);
        if (!isFloat) atomicOr(&flags[1], 1);
    }
    if (i < E) {
        int d = dst[i];
        atomicAdd(&cnt[d], 1);
        atomicAdd(&loct[d / qN], 1);
    }
    __syncthreads();
    if (t < 8 && loct[t]) atomicAdd(&octCnt[t], loct[t]);
}

// ---------------- BcatT[c][k] bf16 (transposed) + w_e scalars ----------------
__global__ void bcatwe_kernel(const float* __restrict__ Wr, const float* __restrict__ Wi,
                              const float* __restrict__ Wrr, const float* __restrict__ Wri,
                              ushort* __restrict__ BT,
                              const float* __restrict__ WeR, const float* __restrict__ aeR,
                              const float* __restrict__ WeI, const float* __restrict__ aeI,
                              float* __restrict__ we) {
    if (blockIdx.x < 256) {
        int idx = blockIdx.x * 256 + threadIdx.x;
        int c = idx >> 7, k = idx & 127;
        const float* srcm;
        if (c < 128)      srcm = Wr;
        else if (c < 256) srcm = Wi;
        else if (c < 384) srcm = Wrr;
        else              srcm = Wri;
        BT[idx] = f2bf(srcm[k * 128 + (c & 127)]);
    } else {
        int lane = threadIdx.x;
        if (lane < 16) {
            float s = 0.f;
            for (int c = 0; c < CDIM; ++c) s += WeR[lane * CDIM + c] * aeR[c];
            we[lane] = s;
        } else if (lane < 32) {
            int j = lane - 16;
            float s = 0.f;
            for (int c = 0; c < CDIM; ++c) s += WeI[j * CDIM + c] * aeI[c];
            we[16 + j] = s;
        }
    }
}

// ---------------- fused MFMA GEMM: xcat[M][512](bf16) = h(f32)[M][128] @ Bcat ----------------
__global__ __launch_bounds__(512) void gemm_fused(const float* __restrict__ h,
                                                  const ushort* __restrict__ BT,
                                                  ushort* __restrict__ C, int M) {
    __shared__ ushort Bs[512 * 128];   // 128 KiB
    __shared__ ushort As[64 * 128];    // 16 KiB
    int t = threadIdx.x, lane = t & 63, wv = t >> 6;
    int rb = blockIdx.x * 64;
    int l15 = lane & 15, l4 = lane >> 4;

#pragma unroll
    for (int p = 0; p < 16; ++p) {
        int g = wv * 16 + p;
        int col = g * 4 + l4;
        int chs = l15 ^ (col & 7);
        const ushort* gb = BT + col * 128 + chs * 8;
        __builtin_amdgcn_global_load_lds(
            (const __attribute__((address_space(1))) void*)gb,
            (__attribute__((address_space(3))) void*)((char*)Bs + g * 1024), 16, 0, 0);
    }

    {
        int row = t >> 3, cp = (t & 7) * 2;
        int gr = rb + row; if (gr > M - 1) gr = M - 1;
        const float4* hp = (const float4*)(h + (size_t)gr * 128 + cp * 8);
        float4 v0 = hp[0], v1 = hp[1], v2 = hp[2], v3 = hp[3];
        uint4 u0, u1;
        u0.x = packbf(v0.x, v0.y); u0.y = packbf(v0.z, v0.w);
        u0.z = packbf(v1.x, v1.y); u0.w = packbf(v1.z, v1.w);
        u1.x = packbf(v2.x, v2.y); u1.y = packbf(v2.z, v2.w);
        u1.z = packbf(v3.x, v3.y); u1.w = packbf(v3.z, v3.w);
        *(uint4*)((char*)As + row * 256 + ((cp)     ^ (row & 7)) * 16) = u0;
        *(uint4*)((char*)As + row * 256 + ((cp + 1) ^ (row & 7)) * 16) = u1;
    }
    __syncthreads();

    f32x4 acc[4][4];
#pragma unroll
    for (int i = 0; i < 4; ++i)
#pragma unroll
        for (int j = 0; j < 4; ++j) acc[i][j] = (f32x4){0.f, 0.f, 0.f, 0.f};

    const char* Ab = (const char*)As;
    const char* Bb = (const char*)Bs;
#pragma unroll
    for (int ks = 0; ks < 4; ++ks) {
        bf16x8 a[4], b[4];
#pragma unroll
        for (int f = 0; f < 4; ++f) {
            int row = f * 16 + l15;
            int ch = (ks * 4 + l4) ^ (row & 7);
            a[f] = *(const bf16x8*)(Ab + row * 256 + ch * 16);
            int col = wv * 64 + f * 16 + l15;
            int ch2 = (ks * 4 + l4) ^ (col & 7);
            b[f] = *(const bf16x8*)(Bb + col * 256 + ch2 * 16);
        }
#pragma unroll
        for (int i = 0; i < 4; ++i)
#pragma unroll
            for (int j = 0; j < 4; ++j)
                acc[i][j] = __builtin_amdgcn_mfma_f32_16x16x32_bf16(a[i], b[j], acc[i][j], 0, 0, 0);
    }

#pragma unroll
    for (int i = 0; i < 4; ++i) {
#pragma unroll
        for (int j = 0; j < 4; ++j) {
            int col = wv * 64 + j * 16 + l15;
#pragma unroll
            for (int r = 0; r < 4; ++r) {
                int gr = rb + i * 16 + l4 * 4 + r;
                if (gr < M) C[(size_t)gr * 512 + col] = f2bf(acc[i][j][r]);
            }
        }
    }
}

// ---------------- per-node attention dots ----------------
__global__ __launch_bounds__(256) void adots_kernel(const ushort* __restrict__ xcat,
                                                    const float* __restrict__ attsr, const float* __restrict__ attdr,
                                                    const float* __restrict__ attsi, const float* __restrict__ attdi,
                                                    float* __restrict__ asr, float* __restrict__ adr,
                                                    float* __restrict__ asi, float* __restrict__ adi, int n) {
    int node = blockIdx.x * 4 + (threadIdx.x >> 6);
    int lane = threadIdx.x & 63;
    if (node >= n) return;
    const uint* xr = (const uint*)(xcat + (size_t)node * 512);
    uint wr_ = xr[lane];
    uint wi_ = xr[64 + lane];
    float r0 = bflo(wr_), r1 = bfhi(wr_);
    float i0 = bflo(wi_), i1 = bfhi(wi_);
    float2 sr = ((const float2*)attsr)[lane], dr = ((const float2*)attdr)[lane];
    float2 si = ((const float2*)attsi)[lane], di = ((const float2*)attdi)[lane];
    float s0 = r0 * sr.x + r1 * sr.y;
    float s1 = r0 * dr.x + r1 * dr.y;
    float s2 = i0 * si.x + i1 * si.y;
    float s3 = i0 * di.x + i1 * di.y;
#pragma unroll
    for (int d = 32; d; d >>= 1) {
        s0 += __shfl_xor(s0, d); s1 += __shfl_xor(s1, d);
        s2 += __shfl_xor(s2, d); s3 += __shfl_xor(s3, d);
    }
    if (lane == 0) { asr[node] = s0; adr[node] = s1; asi[node] = s2; adi[node] = s3; }
}

// ---------------- exclusive scan (node counts) + octant scan ----------------
__global__ __launch_bounds__(1024) void scan_kernel(const int* __restrict__ cnt, int* __restrict__ offv,
                                                    int* __restrict__ cursor, int n,
                                                    const int* __restrict__ octCnt,
                                                    int* __restrict__ octOff, int* __restrict__ octCur) {
    __shared__ int wsum[16];
    __shared__ int s_carry;
    int t = threadIdx.x, lane = t & 63, wid = t >> 6;
    if (t == 0) {
        s_carry = 0;
        int run = 0;
        for (int o = 0; o < 8; ++o) { octOff[o] = run; octCur[o] = run; run += octCnt[o]; }
        octOff[8] = run;
    }
    __syncthreads();
    for (int base = 0; base < n; base += 4096) {
        int i0 = base + t * 4;
        int v[4];
#pragma unroll
        for (int j = 0; j < 4; ++j) { int i = i0 + j; v[j] = (i < n) ? cnt[i] : 0; }
        int s = v[0] + v[1] + v[2] + v[3];
        int incl = s;
#pragma unroll
        for (int d = 1; d < 64; d <<= 1) { int u = __shfl_up(incl, d); if (lane >= d) incl += u; }
        if (lane == 63) wsum[wid] = incl;
        __syncthreads();
        int carry = s_carry;
        int wpre = 0;
        for (int w = 0; w < wid; ++w) wpre += wsum[w];
        int run = carry + wpre + (incl - s);
#pragma unroll
        for (int j = 0; j < 4; ++j) {
            int i = i0 + j;
            if (i < n) { offv[i] = run; cursor[i] = run; }
            run += v[j];
        }
        __syncthreads();
        if (t == 1023) s_carry = carry + wpre + incl;
        __syncthreads();
    }
    if (t == 0) offv[n] = s_carry;
}

// ---------------- phase A: per-edge record, esum, octant-bucketed staging ----------------
__global__ __launch_bounds__(256) void phaseA_kernel(
    const int* __restrict__ src, const int* __restrict__ dst,
    const float* __restrict__ ea, const float* __restrict__ we,
    const void* __restrict__ red, const int* __restrict__ flags,
    const float* __restrict__ asr, const float* __restrict__ asi,
    int* __restrict__ octCur, uint2* __restrict__ stage, float* __restrict__ esum,
    int E, int qN) {
    __shared__ int lcnt[8];
    __shared__ int lbase[8];
    int t = threadIdx.x;
    if (t < 8) lcnt[t] = 0;
    __syncthreads();
    int base = blockIdx.x * (256 * PA_EPT);
    int notInt = flags[0], notFloat = flags[1];

    const float4* we4 = (const float4*)we;
    float4 wr0 = we4[0], wr1 = we4[1], wr2 = we4[2], wr3 = we4[3];
    float4 wi0 = we4[4], wi1 = we4[5], wi2 = we4[6], wi3 = we4[7];

    int octv[PA_EPT], rankv[PA_EPT];
    uint w0v[PA_EPT];
    float apv[PA_EPT];

#pragma unroll
    for (int k = 0; k < PA_EPT; ++k) {
        int e = base + k * 256 + t;
        octv[k] = -1;
        if (e < E) {
            int s = src[e], d = dst[e];
            const float4* row = (const float4*)(ea + (size_t)e * EDIM);
            float4 v0 = row[0], v1 = row[1], v2 = row[2], v3 = row[3];
            float er = v0.x*wr0.x + v0.y*wr0.y + v0.z*wr0.z + v0.w*wr0.w
                     + v1.x*wr1.x + v1.y*wr1.y + v1.z*wr1.z + v1.w*wr1.w
                     + v2.x*wr2.x + v2.y*wr2.y + v2.z*wr2.z + v2.w*wr2.w
                     + v3.x*wr3.x + v3.y*wr3.y + v3.z*wr3.z + v3.w*wr3.w;
            float ei = v0.x*wi0.x + v0.y*wi0.y + v0.z*wi0.z + v0.w*wi0.w
                     + v1.x*wi1.x + v1.y*wi1.y + v1.z*wi1.z + v1.w*wi1.w
                     + v2.x*wi2.x + v2.y*wi2.y + v2.z*wi2.z + v2.w*wi2.w
                     + v3.x*wi3.x + v3.y*wi3.y + v3.z*wi3.z + v3.w*wi3.w;
            bool rr = redtest(red, d, notInt, notFloat);
            float ev = rr ? er : ei;
            atomicAdd(&esum[d], ev);
            float a = (rr ? asr : asi)[s] + ev;
            octv[k] = d / qN;
            w0v[k] = ((uint)d << 16) | (uint)s;
            apv[k] = a;
        }
    }
#pragma unroll
    for (int k = 0; k < PA_EPT; ++k)
        if (octv[k] >= 0) rankv[k] = atomicAdd(&lcnt[octv[k]], 1);
    __syncthreads();
    if (t < 8 && lcnt[t]) lbase[t] = atomicAdd(&octCur[t], lcnt[t]);
    __syncthreads();
#pragma unroll
    for (int k = 0; k < PA_EPT; ++k)
        if (octv[k] >= 0)
            stage[lbase[octv[k]] + rankv[k]] = make_uint2(w0v[k], __float_as_uint(apv[k]));
}

// ---------------- phase B: octant-affine CSR scatter (XCD-local writes) ----------------
__global__ __launch_bounds__(256) void phaseB_kernel(
    const uint2* __restrict__ stage, const int* __restrict__ octOff,
    int* __restrict__ cursor, const void* __restrict__ red, const int* __restrict__ flags,
    uint2* __restrict__ csr, int nslice) {
    int o = blockIdx.x & 7;
    int slice = blockIdx.x >> 3;
    int s0 = octOff[o], s1 = octOff[o + 1];
    int cnt = s1 - s0;
    int per = (cnt + nslice - 1) / nslice;
    int b0 = s0 + slice * per;
    int b1 = min(b0 + per, s1);
    int notInt = flags[0], notFloat = flags[1];
    int t = threadIdx.x;

    for (int base = b0; base < b1; base += 1024) {
        uint2 rec[4]; int jv[4]; bool vv[4]; int pos[4];
#pragma unroll
        for (int q = 0; q < 4; ++q) {
            jv[q] = base + q * 256 + t;
            vv[q] = jv[q] < b1;
            if (vv[q]) rec[q] = stage[jv[q]];
        }
#pragma unroll
        for (int q = 0; q < 4; ++q)
            if (vv[q]) pos[q] = atomicAdd(&cursor[rec[q].x >> 16], 1);
#pragma unroll
        for (int q = 0; q < 4; ++q)
            if (vv[q]) {
                int d = rec[q].x >> 16;
                uint s = rec[q].x & 0xffffu;
                bool rr = redtest(red, d, notInt, notFloat);
                csr[pos[q]] = make_uint2(s | (rr ? 0u : 0x10000u), rec[q].y);
            }
    }
}

// ---------------- node kernel ----------------
__global__ __launch_bounds__(256) void node_kernel(
    const ushort* __restrict__ xcat,
    const float* __restrict__ adst_r, const float* __restrict__ adst_i,
    const float* __restrict__ asrc_r, const float* __restrict__ asrc_i,
    const void* __restrict__ red, const int* __restrict__ flags,
    const int* __restrict__ offv, const uint2* __restrict__ csr,
    const float* __restrict__ esum,
    const float* __restrict__ bias_r, const float* __restrict__ bias_i,
    float* __restrict__ out, int n) {
    __shared__ uint2 buf[4][64];
    int wv = threadIdx.x >> 6, lane = threadIdx.x & 63;
    int node = blockIdx.x * 4 + wv;
    if (node >= n) return;

    int notInt = flags[0], notFloat = flags[1];
    bool r = redtest(red, node, notInt, notFloat);

    float adst = (r ? adst_r : adst_i)[node];
    int b0 = offv[node], b1 = offv[node + 1];
    int k = b1 - b0;
    const char* xb = (const char*)xcat;

    float m = -1e30f, denom = 0.f;
    float acc0 = 0.f, acc1 = 0.f;

    for (int base = b0; base < b1; base += 64) {
        int j = base + lane;
        float ap = -1e30f; uint soff = 0;
        if (j < b1) {
            uint2 rec = csr[j];
            soff = (rec.x & 0xffffu) * 1024u + ((rec.x >> 16) & 1u) * 256u;
            ap = __uint_as_float(rec.y);
        }
        float al = ap + adst;
        al = (al >= 0.f) ? al : NEG_SLOPE * al;
        float cm = al;
#pragma unroll
        for (int d = 32; d; d >>= 1) cm = fmaxf(cm, __shfl_xor(cm, d));
        float mn = fmaxf(m, cm);
        float sc = __expf(m - mn);
        denom *= sc; acc0 *= sc; acc1 *= sc;
        m = mn;
        float ex = __expf(al - mn);
        buf[wv][lane] = make_uint2(__float_as_uint(ex), soff);
        __builtin_amdgcn_wave_barrier();
        int cc = min(64, b1 - base);
        int ccp = (cc + 3) & ~3;
        for (int tq = 0; tq < ccp; tq += 4) {
#pragma unroll
            for (int q = 0; q < 4; ++q) {
                uint2 u = buf[wv][tq + q];
                float w = __uint_as_float(u.x);
                uint v = *(const uint*)(xb + u.y + lane * 4);
                acc0 += w * bflo(v); acc1 += w * bfhi(v);
            }
        }
        float exs = ex;
#pragma unroll
        for (int d = 32; d; d >>= 1) exs += __shfl_xor(exs, d);
        denom += exs;
        __builtin_amdgcn_wave_barrier();
    }

    float eself = esum[node] / fmaxf((float)k, 1.f);
    float asn = (r ? asrc_r : asrc_i)[node];
    float a = asn + adst + eself;
    float aself = (a >= 0.f) ? a : NEG_SLOPE * a;
    float mn = fmaxf(m, aself);
    float sc = __expf(m - mn);
    float exl = __expf(aself - mn);
    denom = denom * sc + exl;
    uint voff = (uint)node * 1024u + (r ? 0u : 256u);
    uint vsw = *(const uint*)(xb + voff + lane * 4);
    acc0 = acc0 * sc + exl * bflo(vsw);
    acc1 = acc1 * sc + exl * bfhi(vsw);

    float inv = 1.f / denom;
    uint roff = (uint)node * 1024u + (r ? 512u : 768u);
    uint bw = *(const uint*)(xb + roff + lane * 4);
    float2 bi2 = ((const float2*)(r ? bias_r : bias_i))[lane];
    float o0 = acc0 * inv + bflo(bw) + bi2.x;
    float o1 = acc1 * inv + bfhi(bw) + bi2.y;
    out[(size_t)node * 128 + lane * 2]     = fmaxf(o0, 0.f);
    out[(size_t)node * 128 + lane * 2 + 1] = fmaxf(o1, 0.f);
}

extern "C" void kernel_launch(void* const* d_in, const int* in_sizes, int n_in,
                              void* d_out, int out_size, void* d_ws, size_t ws_size,
                              hipStream_t stream) {
    const float* h          = (const float*)d_in[0];
    const int*   edge_index = (const int*)d_in[1];
    const float* edge_attr  = (const float*)d_in[2];
    const void*  reducible  = d_in[3];
    const float* red_W      = (const float*)d_in[4];
    const float* red_att_src= (const float*)d_in[5];
    const float* red_att_dst= (const float*)d_in[6];
    const float* red_W_edge = (const float*)d_in[7];
    const float* red_att_edge=(const float*)d_in[8];
    const float* red_W_res  = (const float*)d_in[9];
    const float* red_bias   = (const float*)d_in[10];
    const float* irr_W      = (const float*)d_in[11];
    const float* irr_att_src= (const float*)d_in[12];
    const float* irr_att_dst= (const float*)d_in[13];
    const float* irr_W_edge = (const float*)d_in[14];
    const float* irr_att_edge=(const float*)d_in[15];
    const float* irr_W_res  = (const float*)d_in[16];
    const float* irr_bias   = (const float*)d_in[17];

    const int N = in_sizes[0] / CDIM;
    const int E = in_sizes[1] / 2;
    const int qN = (N + 7) / 8;
    const int* src = edge_index;
    const int* dst = edge_index + E;

    float* out = (float*)d_out;

    size_t cur = 0;
    auto alloc = [&](size_t bytes) { size_t p = cur; cur = (cur + bytes + 255) & ~(size_t)255; return p; };
    char* ws = (char*)d_ws;
    size_t o_xcat  = alloc((size_t)N * 512 * 2);   // bf16 [x_r|x_i|res_r|res_i]
    size_t o_bcat  = alloc(512 * 128 * 2);
    size_t o_we    = alloc(256);
    size_t o_asr   = alloc((size_t)N * 4);
    size_t o_adr   = alloc((size_t)N * 4);
    size_t o_asi   = alloc((size_t)N * 4);
    size_t o_adi   = alloc((size_t)N * 4);
    size_t o_flags = alloc(256);                    // flags[0..1], octCnt at +8
    size_t o_cnt   = alloc((size_t)N * 4);
    size_t o_esum  = alloc((size_t)N * 4);          // contiguous after cnt (one memset)
    size_t o_off   = alloc((size_t)(N + 1) * 4);
    size_t o_cur   = alloc((size_t)N * 4);
    size_t o_ooff  = alloc(64);                     // octOff[9]
    size_t o_ocur  = alloc(64);                     // octCur[8]
    size_t o_stage = alloc((size_t)E * 8);
    size_t o_csr   = alloc((size_t)E * 8);
    if (cur > ws_size) return;

    ushort* xcat = (ushort*)(ws + o_xcat);
    ushort* bcat = (ushort*)(ws + o_bcat);
    float* we    = (float*)(ws + o_we);
    float* asr   = (float*)(ws + o_asr);
    float* adr   = (float*)(ws + o_adr);
    float* asi   = (float*)(ws + o_asi);
    float* adi   = (float*)(ws + o_adi);
    int*   flags = (int*)(ws + o_flags);
    int*   octCnt= flags + 2;                       // 8 ints, zeroed with flags
    int*   cnt   = (int*)(ws + o_cnt);
    float* esum  = (float*)(ws + o_esum);
    int*   offv  = (int*)(ws + o_off);
    int*   curs  = (int*)(ws + o_cur);
    int*   octOff= (int*)(ws + o_ooff);
    int*   octCur= (int*)(ws + o_ocur);
    uint2* stage = (uint2*)(ws + o_stage);
    uint2* csr   = (uint2*)(ws + o_csr);

    hipMemsetAsync(flags, 0, 64, stream);           // flags + octCnt
    hipMemsetAsync(cnt, 0, o_esum + (size_t)N * 4 - o_cnt, stream);  // cnt + esum

    int nwords = N / 4;
    prep_kernel<<<(E + 255) / 256, 256, 0, stream>>>((const uint*)reducible, nwords, flags,
                                                     dst, cnt, octCnt, E, qN);

    bcatwe_kernel<<<257, 256, 0, stream>>>(red_W, irr_W, red_W_res, irr_W_res, bcat,
                                           red_W_edge, red_att_edge, irr_W_edge, irr_att_edge, we);

    gemm_fused<<<(N + 63) / 64, 512, 0, stream>>>(h, bcat, xcat, N);

    adots_kernel<<<(N + 3) / 4, 256, 0, stream>>>(xcat, red_att_src, red_att_dst,
                                                  irr_att_src, irr_att_dst, asr, adr, asi, adi, N);

    scan_kernel<<<1, 1024, 0, stream>>>(cnt, offv, curs, N, octCnt, octOff, octCur);

    phaseA_kernel<<<(E + 256 * PA_EPT - 1) / (256 * PA_EPT), 256, 0, stream>>>(
        src, dst, edge_attr, we, reducible, flags, asr, asi, octCur, stage, esum, E, qN);

    phaseB_kernel<<<512, 256, 0, stream>>>(stage, octOff, curs, reducible, flags, csr, 64);

    node_kernel<<<(N + 3) / 4, 256, 0, stream>>>(xcat, adr, adi, asr, asi,
                                                 reducible, flags, offv, csr, esum,
                                                 red_bias, irr_bias, out, N);
}

// Round 5
// 260.918 us; speedup vs baseline: 1.0783x; 1.0783x over previous
//
#include <hip/hip_runtime.h>
#include <hip/hip_bf16.h>

#define CDIM 128
#define EDIM 16
#define NEG_SLOPE 0.2f

typedef __attribute__((ext_vector_type(8))) short bf16x8;
typedef __attribute__((ext_vector_type(4))) float f32x4;
typedef unsigned int uint;
typedef unsigned short ushort;

__device__ __forceinline__ ushort f2bf(float f) {
    uint u = __float_as_uint(f);
    return (ushort)((u + 0x7fffu + ((u >> 16) & 1u)) >> 16);
}
__device__ __forceinline__ uint packbf(float lo, float hi) {
    return ((uint)f2bf(hi) << 16) | (uint)f2bf(lo);
}
__device__ __forceinline__ float bflo(uint w) { return __uint_as_float(w << 16); }
__device__ __forceinline__ float bfhi(uint w) { return __uint_as_float(w & 0xffff0000u); }

__device__ __forceinline__ bool redtest(const void* red, int i, int notInt, int notFloat) {
    if (!notInt)        return ((const int*)red)[i] != 0;
    else if (!notFloat) return ((const float*)red)[i] != 0.f;
    else                return ((const unsigned char*)red)[i] != 0;
}

// ---------------- BcatT[c][k] bf16 (transposed) + w_e scalars ----------------
__global__ void bcatwe_kernel(const float* __restrict__ Wr, const float* __restrict__ Wi,
                              const float* __restrict__ Wrr, const float* __restrict__ Wri,
                              ushort* __restrict__ BT,
                              const float* __restrict__ WeR, const float* __restrict__ aeR,
                              const float* __restrict__ WeI, const float* __restrict__ aeI,
                              float* __restrict__ we) {
    if (blockIdx.x < 256) {
        int idx = blockIdx.x * 256 + threadIdx.x;
        int c = idx >> 7, k = idx & 127;
        const float* srcm;
        if (c < 128)      srcm = Wr;
        else if (c < 256) srcm = Wi;
        else if (c < 384) srcm = Wrr;
        else              srcm = Wri;
        BT[idx] = f2bf(srcm[k * 128 + (c & 127)]);
    } else {
        int lane = threadIdx.x;
        if (lane < 16) {
            float s = 0.f;
            for (int c = 0; c < CDIM; ++c) s += WeR[lane * CDIM + c] * aeR[c];
            we[lane] = s;
        } else if (lane < 32) {
            int j = lane - 16;
            float s = 0.f;
            for (int c = 0; c < CDIM; ++c) s += WeI[j * CDIM + c] * aeI[c];
            we[16 + j] = s;
        }
    }
}

// ---------------- prep: flags + in-degree histogram + per-edge e-scalars ----------------
__global__ __launch_bounds__(256) void prep_kernel(const uint* __restrict__ red, int nwords,
                                                   int* __restrict__ flags,
                                                   const int* __restrict__ dst, int* __restrict__ cnt,
                                                   const float* __restrict__ ea, const float* __restrict__ we,
                                                   uint2* __restrict__ escal, int E) {
    int i = blockIdx.x * 256 + threadIdx.x;
    if (i < nwords) {
        uint w = red[i];
        bool isInt = (w <= 1u);
        bool isFloat = (w == 0u) || (w == 0x3f800000u);
        if (!isInt) atomicOr(&flags[0], 1);
        if (!isFloat) atomicOr(&flags[1], 1);
    }
    if (i < E) {
        atomicAdd(&cnt[dst[i]], 1);
        const float4* row = (const float4*)(ea + (size_t)i * EDIM);
        const float4* we4 = (const float4*)we;
        float er = 0.f, ei = 0.f;
#pragma unroll
        for (int q = 0; q < 4; ++q) {
            float4 v = row[q];
            float4 wr = we4[q], wi = we4[4 + q];
            er += v.x * wr.x + v.y * wr.y + v.z * wr.z + v.w * wr.w;
            ei += v.x * wi.x + v.y * wi.y + v.z * wi.z + v.w * wi.w;
        }
        escal[i] = make_uint2(__float_as_uint(er), __float_as_uint(ei));
    }
}

// ---------------- fused MFMA GEMM: xcat[M][512](bf16) = h(f32)[M][128] @ Bcat ----------------
__global__ __launch_bounds__(512) void gemm_fused(const float* __restrict__ h,
                                                  const ushort* __restrict__ BT,
                                                  ushort* __restrict__ C, int M) {
    __shared__ ushort Bs[512 * 128];   // 128 KiB
    __shared__ ushort As[64 * 128];    // 16 KiB
    int t = threadIdx.x, lane = t & 63, wv = t >> 6;
    int rb = blockIdx.x * 64;
    int l15 = lane & 15, l4 = lane >> 4;

#pragma unroll
    for (int p = 0; p < 16; ++p) {
        int g = wv * 16 + p;
        int col = g * 4 + l4;
        int chs = l15 ^ (col & 7);
        const ushort* gb = BT + col * 128 + chs * 8;
        __builtin_amdgcn_global_load_lds(
            (const __attribute__((address_space(1))) void*)gb,
            (__attribute__((address_space(3))) void*)((char*)Bs + g * 1024), 16, 0, 0);
    }

    {
        int row = t >> 3, cp = (t & 7) * 2;
        int gr = rb + row; if (gr > M - 1) gr = M - 1;
        const float4* hp = (const float4*)(h + (size_t)gr * 128 + cp * 8);
        float4 v0 = hp[0], v1 = hp[1], v2 = hp[2], v3 = hp[3];
        uint4 u0, u1;
        u0.x = packbf(v0.x, v0.y); u0.y = packbf(v0.z, v0.w);
        u0.z = packbf(v1.x, v1.y); u0.w = packbf(v1.z, v1.w);
        u1.x = packbf(v2.x, v2.y); u1.y = packbf(v2.z, v2.w);
        u1.z = packbf(v3.x, v3.y); u1.w = packbf(v3.z, v3.w);
        *(uint4*)((char*)As + row * 256 + ((cp)     ^ (row & 7)) * 16) = u0;
        *(uint4*)((char*)As + row * 256 + ((cp + 1) ^ (row & 7)) * 16) = u1;
    }
    __syncthreads();

    f32x4 acc[4][4];
#pragma unroll
    for (int i = 0; i < 4; ++i)
#pragma unroll
        for (int j = 0; j < 4; ++j) acc[i][j] = (f32x4){0.f, 0.f, 0.f, 0.f};

    const char* Ab = (const char*)As;
    const char* Bb = (const char*)Bs;
#pragma unroll
    for (int ks = 0; ks < 4; ++ks) {
        bf16x8 a[4], b[4];
#pragma unroll
        for (int f = 0; f < 4; ++f) {
            int row = f * 16 + l15;
            int ch = (ks * 4 + l4) ^ (row & 7);
            a[f] = *(const bf16x8*)(Ab + row * 256 + ch * 16);
            int col = wv * 64 + f * 16 + l15;
            int ch2 = (ks * 4 + l4) ^ (col & 7);
            b[f] = *(const bf16x8*)(Bb + col * 256 + ch2 * 16);
        }
#pragma unroll
        for (int i = 0; i < 4; ++i)
#pragma unroll
            for (int j = 0; j < 4; ++j)
                acc[i][j] = __builtin_amdgcn_mfma_f32_16x16x32_bf16(a[i], b[j], acc[i][j], 0, 0, 0);
    }

#pragma unroll
    for (int i = 0; i < 4; ++i) {
#pragma unroll
        for (int j = 0; j < 4; ++j) {
            int col = wv * 64 + j * 16 + l15;
#pragma unroll
            for (int r = 0; r < 4; ++r) {
                int gr = rb + i * 16 + l4 * 4 + r;
                if (gr < M) C[(size_t)gr * 512 + col] = f2bf(acc[i][j][r]);
            }
        }
    }
}

// ---------------- per-node attention dots ----------------
__global__ __launch_bounds__(256) void adots_kernel(const ushort* __restrict__ xcat,
                                                    const float* __restrict__ attsr, const float* __restrict__ attdr,
                                                    const float* __restrict__ attsi, const float* __restrict__ attdi,
                                                    float* __restrict__ asr, float* __restrict__ adr,
                                                    float* __restrict__ asi, float* __restrict__ adi, int n) {
    int node = blockIdx.x * 4 + (threadIdx.x >> 6);
    int lane = threadIdx.x & 63;
    if (node >= n) return;
    const uint* xr = (const uint*)(xcat + (size_t)node * 512);
    uint wr_ = xr[lane];
    uint wi_ = xr[64 + lane];
    float r0 = bflo(wr_), r1 = bfhi(wr_);
    float i0 = bflo(wi_), i1 = bfhi(wi_);
    float2 sr = ((const float2*)attsr)[lane], dr = ((const float2*)attdr)[lane];
    float2 si = ((const float2*)attsi)[lane], di = ((const float2*)attdi)[lane];
    float s0 = r0 * sr.x + r1 * sr.y;
    float s1 = r0 * dr.x + r1 * dr.y;
    float s2 = i0 * si.x + i1 * si.y;
    float s3 = i0 * di.x + i1 * di.y;
#pragma unroll
    for (int d = 32; d; d >>= 1) {
        s0 += __shfl_xor(s0, d); s1 += __shfl_xor(s1, d);
        s2 += __shfl_xor(s2, d); s3 += __shfl_xor(s3, d);
    }
    if (lane == 0) { asr[node] = s0; adr[node] = s1; asi[node] = s2; adi[node] = s3; }
}

// ---------------- exclusive scan ----------------
__global__ __launch_bounds__(1024) void scan_kernel(const int* __restrict__ cnt, int* __restrict__ offv,
                                                    int* __restrict__ cursor, int n) {
    __shared__ int wsum[16];
    __shared__ int s_carry;
    int t = threadIdx.x, lane = t & 63, wid = t >> 6;
    if (t == 0) s_carry = 0;
    __syncthreads();
    for (int base = 0; base < n; base += 4096) {
        int i0 = base + t * 4;
        int v[4];
#pragma unroll
        for (int j = 0; j < 4; ++j) { int i = i0 + j; v[j] = (i < n) ? cnt[i] : 0; }
        int s = v[0] + v[1] + v[2] + v[3];
        int incl = s;
#pragma unroll
        for (int d = 1; d < 64; d <<= 1) { int u = __shfl_up(incl, d); if (lane >= d) incl += u; }
        if (lane == 63) wsum[wid] = incl;
        __syncthreads();
        int carry = s_carry;
        int wpre = 0;
        for (int w = 0; w < wid; ++w) wpre += wsum[w];
        int run = carry + wpre + (incl - s);
#pragma unroll
        for (int j = 0; j < 4; ++j) {
            int i = i0 + j;
            if (i < n) { offv[i] = run; cursor[i] = run; }
            run += v[j];
        }
        __syncthreads();
        if (t == 1023) s_carry = carry + wpre + incl;
        __syncthreads();
    }
    if (t == 0) offv[n] = s_carry;
}

// ---------------- scatter: one uint2 CSR record per edge ----------------
__global__ __launch_bounds__(256) void scatter_kernel(
    const int* __restrict__ src, const int* __restrict__ dst,
    const uint2* __restrict__ escal, const void* __restrict__ red, const int* __restrict__ flags,
    const float* __restrict__ asr, const float* __restrict__ asi,
    int* __restrict__ cursor, float* __restrict__ esum,
    uint2* __restrict__ csr, int E) {
    int e = blockIdx.x * 256 + threadIdx.x;
    if (e >= E) return;
    int s = src[e], d = dst[e];
    uint2 ee = escal[e];
    int notInt = flags[0], notFloat = flags[1];
    bool rr = redtest(red, d, notInt, notFloat);
    float ev = __uint_as_float(rr ? ee.x : ee.y);
    atomicAdd(&esum[d], ev);
    float ap = (rr ? asr : asi)[s] + ev;
    uint soff = (uint)s * 1024u + (rr ? 0u : 256u);   // byte offset into xcat
    int pos = atomicAdd(&cursor[d], 1);
    csr[pos] = make_uint2(soff, __float_as_uint(ap));
}

// ---------------- node kernel ----------------
__global__ __launch_bounds__(256) void node_kernel(
    const ushort* __restrict__ xcat,
    const float* __restrict__ adst_r, const float* __restrict__ adst_i,
    const float* __restrict__ asrc_r, const float* __restrict__ asrc_i,
    const void* __restrict__ red, const int* __restrict__ flags,
    const int* __restrict__ offv, const uint2* __restrict__ csr,
    const float* __restrict__ esum,
    const float* __restrict__ bias_r, const float* __restrict__ bias_i,
    float* __restrict__ out, int n) {
    __shared__ uint2 buf[4][64];
    int wv = threadIdx.x >> 6, lane = threadIdx.x & 63;
    int node = blockIdx.x * 4 + wv;
    if (node >= n) return;

    int notInt = flags[0], notFloat = flags[1];
    bool r = redtest(red, node, notInt, notFloat);

    float adst = (r ? adst_r : adst_i)[node];
    int b0 = offv[node], b1 = offv[node + 1];
    int k = b1 - b0;
    const char* xb = (const char*)xcat;

    float m = -1e30f, denom = 0.f;
    float acc0 = 0.f, acc1 = 0.f;

    for (int base = b0; base < b1; base += 64) {
        int j = base + lane;
        float ap = -1e30f; uint soff = 0;
        if (j < b1) {
            uint2 rec = csr[j];
            soff = rec.x;
            ap = __uint_as_float(rec.y);
        }
        float al = ap + adst;
        al = (al >= 0.f) ? al : NEG_SLOPE * al;
        float cm = al;
#pragma unroll
        for (int d = 32; d; d >>= 1) cm = fmaxf(cm, __shfl_xor(cm, d));
        float mn = fmaxf(m, cm);
        float sc = __expf(m - mn);
        denom *= sc; acc0 *= sc; acc1 *= sc;
        m = mn;
        float ex = __expf(al - mn);
        buf[wv][lane] = make_uint2(__float_as_uint(ex), soff);
        __builtin_amdgcn_wave_barrier();
        int cc = min(64, b1 - base);
        int ccp = (cc + 3) & ~3;
        for (int tq = 0; tq < ccp; tq += 4) {
#pragma unroll
            for (int q = 0; q < 4; ++q) {
                uint2 u = buf[wv][tq + q];
                float w = __uint_as_float(u.x);
                uint v = *(const uint*)(xb + u.y + lane * 4);
                acc0 += w * bflo(v); acc1 += w * bfhi(v);
            }
        }
        float exs = ex;
#pragma unroll
        for (int d = 32; d; d >>= 1) exs += __shfl_xor(exs, d);
        denom += exs;
        __builtin_amdgcn_wave_barrier();
    }

    float eself = esum[node] / fmaxf((float)k, 1.f);
    float asn = (r ? asrc_r : asrc_i)[node];
    float a = asn + adst + eself;
    float aself = (a >= 0.f) ? a : NEG_SLOPE * a;
    float mn = fmaxf(m, aself);
    float sc = __expf(m - mn);
    float exl = __expf(aself - mn);
    denom = denom * sc + exl;
    uint voff = (uint)node * 1024u + (r ? 0u : 256u);
    uint vsw = *(const uint*)(xb + voff + lane * 4);
    acc0 = acc0 * sc + exl * bflo(vsw);
    acc1 = acc1 * sc + exl * bfhi(vsw);

    float inv = 1.f / denom;
    uint roff = (uint)node * 1024u + (r ? 512u : 768u);
    uint bw = *(const uint*)(xb + roff + lane * 4);
    float2 bi2 = ((const float2*)(r ? bias_r : bias_i))[lane];
    float o0 = acc0 * inv + bflo(bw) + bi2.x;
    float o1 = acc1 * inv + bfhi(bw) + bi2.y;
    out[(size_t)node * 128 + lane * 2]     = fmaxf(o0, 0.f);
    out[(size_t)node * 128 + lane * 2 + 1] = fmaxf(o1, 0.f);
}

extern "C" void kernel_launch(void* const* d_in, const int* in_sizes, int n_in,
                              void* d_out, int out_size, void* d_ws, size_t ws_size,
                              hipStream_t stream) {
    const float* h          = (const float*)d_in[0];
    const int*   edge_index = (const int*)d_in[1];
    const float* edge_attr  = (const float*)d_in[2];
    const void*  reducible  = d_in[3];
    const float* red_W      = (const float*)d_in[4];
    const float* red_att_src= (const float*)d_in[5];
    const float* red_att_dst= (const float*)d_in[6];
    const float* red_W_edge = (const float*)d_in[7];
    const float* red_att_edge=(const float*)d_in[8];
    const float* red_W_res  = (const float*)d_in[9];
    const float* red_bias   = (const float*)d_in[10];
    const float* irr_W      = (const float*)d_in[11];
    const float* irr_att_src= (const float*)d_in[12];
    const float* irr_att_dst= (const float*)d_in[13];
    const float* irr_W_edge = (const float*)d_in[14];
    const float* irr_att_edge=(const float*)d_in[15];
    const float* irr_W_res  = (const float*)d_in[16];
    const float* irr_bias   = (const float*)d_in[17];

    const int N = in_sizes[0] / CDIM;
    const int E = in_sizes[1] / 2;
    const int* src = edge_index;
    const int* dst = edge_index + E;

    float* out = (float*)d_out;

    size_t cur = 0;
    auto alloc = [&](size_t bytes) { size_t p = cur; cur = (cur + bytes + 255) & ~(size_t)255; return p; };
    char* ws = (char*)d_ws;
    size_t o_xcat  = alloc((size_t)N * 512 * 2);   // bf16 [x_r|x_i|res_r|res_i]
    size_t o_bcat  = alloc(512 * 128 * 2);
    size_t o_we    = alloc(256);
    size_t o_asr   = alloc((size_t)N * 4);
    size_t o_adr   = alloc((size_t)N * 4);
    size_t o_asi   = alloc((size_t)N * 4);
    size_t o_adi   = alloc((size_t)N * 4);
    size_t o_flags = alloc(256);
    size_t o_cnt   = alloc((size_t)N * 4);
    size_t o_esum  = alloc((size_t)N * 4);          // contiguous after cnt (one memset)
    size_t o_off   = alloc((size_t)(N + 1) * 4);
    size_t o_cur   = alloc((size_t)N * 4);
    size_t o_escal = alloc((size_t)E * 8);
    size_t o_csr   = alloc((size_t)E * 8);
    if (cur > ws_size) return;

    ushort* xcat = (ushort*)(ws + o_xcat);
    ushort* bcat = (ushort*)(ws + o_bcat);
    float* we    = (float*)(ws + o_we);
    float* asr   = (float*)(ws + o_asr);
    float* adr   = (float*)(ws + o_adr);
    float* asi   = (float*)(ws + o_asi);
    float* adi   = (float*)(ws + o_adi);
    int*   flags = (int*)(ws + o_flags);
    int*   cnt   = (int*)(ws + o_cnt);
    float* esum  = (float*)(ws + o_esum);
    int*   offv  = (int*)(ws + o_off);
    int*   curs  = (int*)(ws + o_cur);
    uint2* escal = (uint2*)(ws + o_escal);
    uint2* csr   = (uint2*)(ws + o_csr);

    hipMemsetAsync(flags, 0, 8, stream);
    hipMemsetAsync(cnt, 0, o_esum + (size_t)N * 4 - o_cnt, stream);  // cnt + esum

    bcatwe_kernel<<<257, 256, 0, stream>>>(red_W, irr_W, red_W_res, irr_W_res, bcat,
                                           red_W_edge, red_att_edge, irr_W_edge, irr_att_edge, we);

    int nwords = N / 4;
    prep_kernel<<<(E + 255) / 256, 256, 0, stream>>>((const uint*)reducible, nwords, flags,
                                                     dst, cnt, edge_attr, we, escal, E);

    gemm_fused<<<(N + 63) / 64, 512, 0, stream>>>(h, bcat, xcat, N);

    adots_kernel<<<(N + 3) / 4, 256, 0, stream>>>(xcat, red_att_src, red_att_dst,
                                                  irr_att_src, irr_att_dst, asr, adr, asi, adi, N);

    scan_kernel<<<1, 1024, 0, stream>>>(cnt, offv, curs, N);

    scatter_kernel<<<(E + 255) / 256, 256, 0, stream>>>(src, dst, escal, reducible, flags,
                                                        asr, asi, curs, esum, csr, E);

    node_kernel<<<(N + 3) / 4, 256, 0, stream>>>(xcat, adr, adi, asr, asi,
                                                 reducible, flags, offv, csr, esum,
                                                 red_bias, irr_bias, out, N);
}

// Round 6
// 185.494 us; speedup vs baseline: 1.5167x; 1.4066x over previous
//
#include <hip/hip_runtime.h>
#include <hip/hip_bf16.h>

#define CDIM 128
#define EDIM 16
#define NEG_SLOPE 0.2f

typedef __attribute__((ext_vector_type(8))) short bf16x8;
typedef __attribute__((ext_vector_type(4))) float f32x4;
typedef unsigned int uint;
typedef unsigned short ushort;

__device__ __forceinline__ ushort f2bf(float f) {
    uint u = __float_as_uint(f);
    return (ushort)((u + 0x7fffu + ((u >> 16) & 1u)) >> 16);
}
__device__ __forceinline__ uint packbf(float lo, float hi) {
    return ((uint)f2bf(hi) << 16) | (uint)f2bf(lo);
}
__device__ __forceinline__ float bflo(uint w) { return __uint_as_float(w << 16); }
__device__ __forceinline__ float bfhi(uint w) { return __uint_as_float(w & 0xffff0000u); }

__device__ __forceinline__ bool redtest(const void* red, int i, int notInt, int notFloat) {
    if (!notInt)        return ((const int*)red)[i] != 0;
    else if (!notFloat) return ((const float*)red)[i] != 0.f;
    else                return ((const unsigned char*)red)[i] != 0;
}

// ---------------- BcatT[c][k] bf16 (transposed) + w_e scalars ----------------
__global__ void bcatwe_kernel(const float* __restrict__ Wr, const float* __restrict__ Wi,
                              const float* __restrict__ Wrr, const float* __restrict__ Wri,
                              ushort* __restrict__ BT,
                              const float* __restrict__ WeR, const float* __restrict__ aeR,
                              const float* __restrict__ WeI, const float* __restrict__ aeI,
                              float* __restrict__ we) {
    if (blockIdx.x < 256) {
        int idx = blockIdx.x * 256 + threadIdx.x;
        int c = idx >> 7, k = idx & 127;
        const float* srcm;
        if (c < 128)      srcm = Wr;
        else if (c < 256) srcm = Wi;
        else if (c < 384) srcm = Wrr;
        else              srcm = Wri;
        BT[idx] = f2bf(srcm[k * 128 + (c & 127)]);
    } else {
        int lane = threadIdx.x;
        if (lane < 16) {
            float s = 0.f;
            for (int c = 0; c < CDIM; ++c) s += WeR[lane * CDIM + c] * aeR[c];
            we[lane] = s;
        } else if (lane < 32) {
            int j = lane - 16;
            float s = 0.f;
            for (int c = 0; c < CDIM; ++c) s += WeI[j * CDIM + c] * aeI[c];
            we[16 + j] = s;
        }
    }
}

// ---------------- prep: flags + in-degree histogram (rank = return) + e-scalars ----------------
__global__ __launch_bounds__(256) void prep_kernel(const uint* __restrict__ red, int nwords,
                                                   int* __restrict__ flags,
                                                   const int* __restrict__ dst, int* __restrict__ cnt,
                                                   int* __restrict__ rank,
                                                   const float* __restrict__ ea, const float* __restrict__ we,
                                                   uint2* __restrict__ escal, int E) {
    int i = blockIdx.x * 256 + threadIdx.x;
    if (i < nwords) {
        uint w = red[i];
        bool isInt = (w <= 1u);
        bool isFloat = (w == 0u) || (w == 0x3f800000u);
        if (!isInt) atomicOr(&flags[0], 1);
        if (!isFloat) atomicOr(&flags[1], 1);
    }
    if (i < E) {
        rank[i] = atomicAdd(&cnt[dst[i]], 1);
        const float4* row = (const float4*)(ea + (size_t)i * EDIM);
        const float4* we4 = (const float4*)we;
        float er = 0.f, ei = 0.f;
#pragma unroll
        for (int q = 0; q < 4; ++q) {
            float4 v = row[q];
            float4 wr = we4[q], wi = we4[4 + q];
            er += v.x * wr.x + v.y * wr.y + v.z * wr.z + v.w * wr.w;
            ei += v.x * wi.x + v.y * wi.y + v.z * wi.z + v.w * wi.w;
        }
        escal[i] = make_uint2(__float_as_uint(er), __float_as_uint(ei));
    }
}

// ---------------- fused MFMA GEMM: xcat[M][512](bf16) = h(f32)[M][128] @ Bcat ----------------
__global__ __launch_bounds__(512) void gemm_fused(const float* __restrict__ h,
                                                  const ushort* __restrict__ BT,
                                                  ushort* __restrict__ C, int M) {
    __shared__ ushort Bs[512 * 128];   // 128 KiB
    __shared__ ushort As[64 * 128];    // 16 KiB
    int t = threadIdx.x, lane = t & 63, wv = t >> 6;
    int rb = blockIdx.x * 64;
    int l15 = lane & 15, l4 = lane >> 4;

#pragma unroll
    for (int p = 0; p < 16; ++p) {
        int g = wv * 16 + p;
        int col = g * 4 + l4;
        int chs = l15 ^ (col & 7);
        const ushort* gb = BT + col * 128 + chs * 8;
        __builtin_amdgcn_global_load_lds(
            (const __attribute__((address_space(1))) void*)gb,
            (__attribute__((address_space(3))) void*)((char*)Bs + g * 1024), 16, 0, 0);
    }

    {
        int row = t >> 3, cp = (t & 7) * 2;
        int gr = rb + row; if (gr > M - 1) gr = M - 1;
        const float4* hp = (const float4*)(h + (size_t)gr * 128 + cp * 8);
        float4 v0 = hp[0], v1 = hp[1], v2 = hp[2], v3 = hp[3];
        uint4 u0, u1;
        u0.x = packbf(v0.x, v0.y); u0.y = packbf(v0.z, v0.w);
        u0.z = packbf(v1.x, v1.y); u0.w = packbf(v1.z, v1.w);
        u1.x = packbf(v2.x, v2.y); u1.y = packbf(v2.z, v2.w);
        u1.z = packbf(v3.x, v3.y); u1.w = packbf(v3.z, v3.w);
        *(uint4*)((char*)As + row * 256 + ((cp)     ^ (row & 7)) * 16) = u0;
        *(uint4*)((char*)As + row * 256 + ((cp + 1) ^ (row & 7)) * 16) = u1;
    }
    __syncthreads();

    f32x4 acc[4][4];
#pragma unroll
    for (int i = 0; i < 4; ++i)
#pragma unroll
        for (int j = 0; j < 4; ++j) acc[i][j] = (f32x4){0.f, 0.f, 0.f, 0.f};

    const char* Ab = (const char*)As;
    const char* Bb = (const char*)Bs;
#pragma unroll
    for (int ks = 0; ks < 4; ++ks) {
        bf16x8 a[4], b[4];
#pragma unroll
        for (int f = 0; f < 4; ++f) {
            int row = f * 16 + l15;
            int ch = (ks * 4 + l4) ^ (row & 7);
            a[f] = *(const bf16x8*)(Ab + row * 256 + ch * 16);
            int col = wv * 64 + f * 16 + l15;
            int ch2 = (ks * 4 + l4) ^ (col & 7);
            b[f] = *(const bf16x8*)(Bb + col * 256 + ch2 * 16);
        }
#pragma unroll
        for (int i = 0; i < 4; ++i)
#pragma unroll
            for (int j = 0; j < 4; ++j)
                acc[i][j] = __builtin_amdgcn_mfma_f32_16x16x32_bf16(a[i], b[j], acc[i][j], 0, 0, 0);
    }

#pragma unroll
    for (int i = 0; i < 4; ++i) {
#pragma unroll
        for (int j = 0; j < 4; ++j) {
            int col = wv * 64 + j * 16 + l15;
#pragma unroll
            for (int r = 0; r < 4; ++r) {
                int gr = rb + i * 16 + l4 * 4 + r;
                if (gr < M) C[(size_t)gr * 512 + col] = f2bf(acc[i][j][r]);
            }
        }
    }
}

// ---------------- per-node attention dots ----------------
__global__ __launch_bounds__(256) void adots_kernel(const ushort* __restrict__ xcat,
                                                    const float* __restrict__ attsr, const float* __restrict__ attdr,
                                                    const float* __restrict__ attsi, const float* __restrict__ attdi,
                                                    float* __restrict__ asr, float* __restrict__ adr,
                                                    float* __restrict__ asi, float* __restrict__ adi, int n) {
    int node = blockIdx.x * 4 + (threadIdx.x >> 6);
    int lane = threadIdx.x & 63;
    if (node >= n) return;
    const uint* xr = (const uint*)(xcat + (size_t)node * 512);
    uint wr_ = xr[lane];
    uint wi_ = xr[64 + lane];
    float r0 = bflo(wr_), r1 = bfhi(wr_);
    float i0 = bflo(wi_), i1 = bfhi(wi_);
    float2 sr = ((const float2*)attsr)[lane], dr = ((const float2*)attdr)[lane];
    float2 si = ((const float2*)attsi)[lane], di = ((const float2*)attdi)[lane];
    float s0 = r0 * sr.x + r1 * sr.y;
    float s1 = r0 * dr.x + r1 * dr.y;
    float s2 = i0 * si.x + i1 * si.y;
    float s3 = i0 * di.x + i1 * di.y;
#pragma unroll
    for (int d = 32; d; d >>= 1) {
        s0 += __shfl_xor(s0, d); s1 += __shfl_xor(s1, d);
        s2 += __shfl_xor(s2, d); s3 += __shfl_xor(s3, d);
    }
    if (lane == 0) { asr[node] = s0; adr[node] = s1; asi[node] = s2; adi[node] = s3; }
}

// ---------------- exclusive scan ----------------
__global__ __launch_bounds__(1024) void scan_kernel(const int* __restrict__ cnt, int* __restrict__ offv, int n) {
    __shared__ int wsum[16];
    __shared__ int s_carry;
    int t = threadIdx.x, lane = t & 63, wid = t >> 6;
    if (t == 0) s_carry = 0;
    __syncthreads();
    for (int base = 0; base < n; base += 4096) {
        int i0 = base + t * 4;
        int v[4];
#pragma unroll
        for (int j = 0; j < 4; ++j) { int i = i0 + j; v[j] = (i < n) ? cnt[i] : 0; }
        int s = v[0] + v[1] + v[2] + v[3];
        int incl = s;
#pragma unroll
        for (int d = 1; d < 64; d <<= 1) { int u = __shfl_up(incl, d); if (lane >= d) incl += u; }
        if (lane == 63) wsum[wid] = incl;
        __syncthreads();
        int carry = s_carry;
        int wpre = 0;
        for (int w = 0; w < wid; ++w) wpre += wsum[w];
        int run = carry + wpre + (incl - s);
#pragma unroll
        for (int j = 0; j < 4; ++j) {
            int i = i0 + j;
            if (i < n) offv[i] = run;
            run += v[j];
        }
        __syncthreads();
        if (t == 1023) s_carry = carry + wpre + incl;
        __syncthreads();
    }
    if (t == 0) offv[n] = s_carry;
}

// ---------------- scatter: atomic-free 4B-record CSR permutation ----------------
__global__ __launch_bounds__(256) void scatter_kernel(
    const int* __restrict__ src, const int* __restrict__ dst,
    const int* __restrict__ rank, const uint2* __restrict__ escal,
    const void* __restrict__ red, const int* __restrict__ flags,
    const int* __restrict__ offv, uint* __restrict__ csr, int E) {
    int e = blockIdx.x * 256 + threadIdx.x;
    if (e >= E) return;
    int s = src[e], d = dst[e];
    uint2 ee = escal[e];
    int notInt = flags[0], notFloat = flags[1];
    bool rr = redtest(red, d, notInt, notFloat);
    float ev = __uint_as_float(rr ? ee.x : ee.y);
    uint rec = (uint)s | ((uint)f2bf(ev) << 16);
    csr[offv[d] + rank[e]] = rec;
}

// ---------------- node kernel ----------------
__global__ __launch_bounds__(256) void node_kernel(
    const ushort* __restrict__ xcat,
    const float* __restrict__ adst_r, const float* __restrict__ adst_i,
    const float* __restrict__ asrc_r, const float* __restrict__ asrc_i,
    const void* __restrict__ red, const int* __restrict__ flags,
    const int* __restrict__ offv, const uint* __restrict__ csr,
    const float* __restrict__ bias_r, const float* __restrict__ bias_i,
    float* __restrict__ out, int n) {
    __shared__ uint2 buf[4][64];
    int wv = threadIdx.x >> 6, lane = threadIdx.x & 63;
    int node = blockIdx.x * 4 + wv;
    if (node >= n) return;

    int notInt = flags[0], notFloat = flags[1];
    bool r = redtest(red, node, notInt, notFloat);

    const float* asrc = r ? asrc_r : asrc_i;
    float adst = (r ? adst_r : adst_i)[node];
    uint vsel = r ? 0u : 256u;
    int b0 = offv[node], b1 = offv[node + 1];
    int k = b1 - b0;
    const char* xb = (const char*)xcat;

    float m = -1e30f, denom = 0.f;
    float acc0 = 0.f, acc1 = 0.f;
    float sumE = 0.f;

    for (int base = b0; base < b1; base += 64) {
        int j = base + lane;
        float al = -1e30f; uint soff = 0;
        if (j < b1) {
            uint rec = csr[j];
            uint s = rec & 0xffffu;
            float ev = bfhi(rec);
            sumE += ev;
            soff = s * 1024u + vsel;
            float a = asrc[s] + ev + adst;
            al = (a >= 0.f) ? a : NEG_SLOPE * a;
        }
        float cm = al;
#pragma unroll
        for (int d = 32; d; d >>= 1) cm = fmaxf(cm, __shfl_xor(cm, d));
        float mn = fmaxf(m, cm);
        float sc = __expf(m - mn);
        denom *= sc; acc0 *= sc; acc1 *= sc;
        m = mn;
        float ex = (j < b1) ? __expf(al - mn) : 0.f;
        buf[wv][lane] = make_uint2(__float_as_uint(ex), soff);
        __builtin_amdgcn_wave_barrier();
        int cc = min(64, b1 - base);
        int ccp = (cc + 3) & ~3;
        for (int tq = 0; tq < ccp; tq += 4) {
#pragma unroll
            for (int q = 0; q < 4; ++q) {
                uint2 u = buf[wv][tq + q];
                float w = __uint_as_float(u.x);
                uint v = *(const uint*)(xb + u.y + lane * 4);
                acc0 += w * bflo(v); acc1 += w * bfhi(v);
            }
        }
        float exs = ex;
#pragma unroll
        for (int d = 32; d; d >>= 1) exs += __shfl_xor(exs, d);
        denom += exs;
        __builtin_amdgcn_wave_barrier();
    }

    // self loop
#pragma unroll
    for (int d = 32; d; d >>= 1) sumE += __shfl_xor(sumE, d);
    float eself = sumE / fmaxf((float)k, 1.f);
    float asn = asrc[node];
    float a = asn + adst + eself;
    float aself = (a >= 0.f) ? a : NEG_SLOPE * a;
    float mn = fmaxf(m, aself);
    float sc = __expf(m - mn);
    float exl = __expf(aself - mn);
    denom = denom * sc + exl;
    uint voff = (uint)node * 1024u + vsel;
    uint vsw = *(const uint*)(xb + voff + lane * 4);
    acc0 = acc0 * sc + exl * bflo(vsw);
    acc1 = acc1 * sc + exl * bfhi(vsw);

    float inv = 1.f / denom;
    uint roff = (uint)node * 1024u + (r ? 512u : 768u);
    uint bw = *(const uint*)(xb + roff + lane * 4);
    float2 bi2 = ((const float2*)(r ? bias_r : bias_i))[lane];
    float o0 = acc0 * inv + bflo(bw) + bi2.x;
    float o1 = acc1 * inv + bfhi(bw) + bi2.y;
    out[(size_t)node * 128 + lane * 2]     = fmaxf(o0, 0.f);
    out[(size_t)node * 128 + lane * 2 + 1] = fmaxf(o1, 0.f);
}

extern "C" void kernel_launch(void* const* d_in, const int* in_sizes, int n_in,
                              void* d_out, int out_size, void* d_ws, size_t ws_size,
                              hipStream_t stream) {
    const float* h          = (const float*)d_in[0];
    const int*   edge_index = (const int*)d_in[1];
    const float* edge_attr  = (const float*)d_in[2];
    const void*  reducible  = d_in[3];
    const float* red_W      = (const float*)d_in[4];
    const float* red_att_src= (const float*)d_in[5];
    const float* red_att_dst= (const float*)d_in[6];
    const float* red_W_edge = (const float*)d_in[7];
    const float* red_att_edge=(const float*)d_in[8];
    const float* red_W_res  = (const float*)d_in[9];
    const float* red_bias   = (const float*)d_in[10];
    const float* irr_W      = (const float*)d_in[11];
    const float* irr_att_src= (const float*)d_in[12];
    const float* irr_att_dst= (const float*)d_in[13];
    const float* irr_W_edge = (const float*)d_in[14];
    const float* irr_att_edge=(const float*)d_in[15];
    const float* irr_W_res  = (const float*)d_in[16];
    const float* irr_bias   = (const float*)d_in[17];

    const int N = in_sizes[0] / CDIM;
    const int E = in_sizes[1] / 2;
    const int* src = edge_index;
    const int* dst = edge_index + E;

    float* out = (float*)d_out;

    size_t cur = 0;
    auto alloc = [&](size_t bytes) { size_t p = cur; cur = (cur + bytes + 255) & ~(size_t)255; return p; };
    char* ws = (char*)d_ws;
    size_t o_xcat  = alloc((size_t)N * 512 * 2);   // bf16 [x_r|x_i|res_r|res_i]
    size_t o_bcat  = alloc(512 * 128 * 2);
    size_t o_we    = alloc(256);
    size_t o_asr   = alloc((size_t)N * 4);
    size_t o_adr   = alloc((size_t)N * 4);
    size_t o_asi   = alloc((size_t)N * 4);
    size_t o_adi   = alloc((size_t)N * 4);
    size_t o_flags = alloc(256);
    size_t o_cnt   = alloc((size_t)N * 4);
    size_t o_off   = alloc((size_t)(N + 1) * 4);
    size_t o_rank  = alloc((size_t)E * 4);
    size_t o_escal = alloc((size_t)E * 8);
    size_t o_csr   = alloc((size_t)E * 4);
    if (cur > ws_size) return;

    ushort* xcat = (ushort*)(ws + o_xcat);
    ushort* bcat = (ushort*)(ws + o_bcat);
    float* we    = (float*)(ws + o_we);
    float* asr   = (float*)(ws + o_asr);
    float* adr   = (float*)(ws + o_adr);
    float* asi   = (float*)(ws + o_asi);
    float* adi   = (float*)(ws + o_adi);
    int*   flags = (int*)(ws + o_flags);
    int*   cnt   = (int*)(ws + o_cnt);
    int*   offv  = (int*)(ws + o_off);
    int*   rank  = (int*)(ws + o_rank);
    uint2* escal = (uint2*)(ws + o_escal);
    uint*  csr   = (uint*)(ws + o_csr);

    hipMemsetAsync(flags, 0, 8, stream);
    hipMemsetAsync(cnt, 0, (size_t)N * 4, stream);

    bcatwe_kernel<<<257, 256, 0, stream>>>(red_W, irr_W, red_W_res, irr_W_res, bcat,
                                           red_W_edge, red_att_edge, irr_W_edge, irr_att_edge, we);

    int nwords = N / 4;
    prep_kernel<<<(E + 255) / 256, 256, 0, stream>>>((const uint*)reducible, nwords, flags,
                                                     dst, cnt, rank, edge_attr, we, escal, E);

    gemm_fused<<<(N + 63) / 64, 512, 0, stream>>>(h, bcat, xcat, N);

    adots_kernel<<<(N + 3) / 4, 256, 0, stream>>>(xcat, red_att_src, red_att_dst,
                                                  irr_att_src, irr_att_dst, asr, adr, asi, adi, N);

    scan_kernel<<<1, 1024, 0, stream>>>(cnt, offv, N);

    scatter_kernel<<<(E + 255) / 256, 256, 0, stream>>>(src, dst, rank, escal,
                                                        reducible, flags, offv, csr, E);

    node_kernel<<<(N + 3) / 4, 256, 0, stream>>>(xcat, adr, adi, asr, asi,
                                                 reducible, flags, offv, csr,
                                                 red_bias, irr_bias, out, N);
}

// Round 7
// 156.619 us; speedup vs baseline: 1.7963x; 1.1844x over previous
//
#include <hip/hip_runtime.h>
#include <hip/hip_bf16.h>

#define CDIM 128
#define EDIM 16
#define NEG_SLOPE 0.2f

typedef __attribute__((ext_vector_type(8))) short bf16x8;
typedef __attribute__((ext_vector_type(4))) float f32x4;
typedef unsigned int uint;
typedef unsigned short ushort;

__device__ __forceinline__ ushort f2bf(float f) {
    uint u = __float_as_uint(f);
    return (ushort)((u + 0x7fffu + ((u >> 16) & 1u)) >> 16);
}
__device__ __forceinline__ uint packbf(float lo, float hi) {
    return ((uint)f2bf(hi) << 16) | (uint)f2bf(lo);
}
__device__ __forceinline__ float bflo(uint w) { return __uint_as_float(w << 16); }
__device__ __forceinline__ float bfhi(uint w) { return __uint_as_float(w & 0xffff0000u); }

__device__ __forceinline__ bool redtest(const void* red, int i, int notInt, int notFloat) {
    if (!notInt)        return ((const int*)red)[i] != 0;
    else if (!notFloat) return ((const float*)red)[i] != 0.f;
    else                return ((const unsigned char*)red)[i] != 0;
}

// ---------------- BcatT[c][k] bf16 (transposed) + w_e scalars ----------------
__global__ void bcatwe_kernel(const float* __restrict__ Wr, const float* __restrict__ Wi,
                              const float* __restrict__ Wrr, const float* __restrict__ Wri,
                              ushort* __restrict__ BT,
                              const float* __restrict__ WeR, const float* __restrict__ aeR,
                              const float* __restrict__ WeI, const float* __restrict__ aeI,
                              float* __restrict__ we) {
    if (blockIdx.x < 256) {
        int idx = blockIdx.x * 256 + threadIdx.x;
        int c = idx >> 7, k = idx & 127;
        const float* srcm;
        if (c < 128)      srcm = Wr;
        else if (c < 256) srcm = Wi;
        else if (c < 384) srcm = Wrr;
        else              srcm = Wri;
        BT[idx] = f2bf(srcm[k * 128 + (c & 127)]);
    } else {
        int lane = threadIdx.x;
        if (lane < 16) {
            float s = 0.f;
            for (int c = 0; c < CDIM; ++c) s += WeR[lane * CDIM + c] * aeR[c];
            we[lane] = s;
        } else if (lane < 32) {
            int j = lane - 16;
            float s = 0.f;
            for (int c = 0; c < CDIM; ++c) s += WeI[j * CDIM + c] * aeI[c];
            we[16 + j] = s;
        }
    }
}

// ---------------- prep: flags + in-degree histogram (rank = return) + e-scalars (2xbf16) ----
__global__ __launch_bounds__(256) void prep_kernel(const uint* __restrict__ red, int nwords,
                                                   int* __restrict__ flags,
                                                   const int* __restrict__ dst, int* __restrict__ cnt,
                                                   int* __restrict__ rank,
                                                   const float* __restrict__ ea, const float* __restrict__ we,
                                                   uint* __restrict__ escal4, int E) {
    int i = blockIdx.x * 256 + threadIdx.x;
    if (i < nwords) {
        uint w = red[i];
        bool isInt = (w <= 1u);
        bool isFloat = (w == 0u) || (w == 0x3f800000u);
        if (!isInt) atomicOr(&flags[0], 1);
        if (!isFloat) atomicOr(&flags[1], 1);
    }
    if (i < E) {
        rank[i] = atomicAdd(&cnt[dst[i]], 1);
        const float4* row = (const float4*)(ea + (size_t)i * EDIM);
        const float4* we4 = (const float4*)we;
        float er = 0.f, ei = 0.f;
#pragma unroll
        for (int q = 0; q < 4; ++q) {
            float4 v = row[q];
            float4 wr = we4[q], wi = we4[4 + q];
            er += v.x * wr.x + v.y * wr.y + v.z * wr.z + v.w * wr.w;
            ei += v.x * wi.x + v.y * wi.y + v.z * wi.z + v.w * wi.w;
        }
        escal4[i] = packbf(er, ei);   // lo=er, hi=ei
    }
}

// ---------------- fused MFMA GEMM + attention-dot epilogue ----------------
// xcat[M][512](bf16) = h(f32)[M][128] @ Bcat; also a_src/a_dst for both variants from f32 acc.
__global__ __launch_bounds__(512) void gemm_fused(const float* __restrict__ h,
                                                  const ushort* __restrict__ BT,
                                                  ushort* __restrict__ C,
                                                  const float* __restrict__ attsr, const float* __restrict__ attdr,
                                                  const float* __restrict__ attsi, const float* __restrict__ attdi,
                                                  float* __restrict__ asr, float* __restrict__ adr,
                                                  float* __restrict__ asi, float* __restrict__ adi, int M) {
    __shared__ ushort Bs[512 * 128];   // 128 KiB
    __shared__ ushort As[64 * 128];    // 16 KiB
    __shared__ float dots[4][64];      // 1 KiB: [asr|adr|asi|adi][row]
    int t = threadIdx.x, lane = t & 63, wv = t >> 6;
    int rb = blockIdx.x * 64;
    int l15 = lane & 15, l4 = lane >> 4;

    if (t < 256) dots[t >> 6][t & 63] = 0.f;

#pragma unroll
    for (int p = 0; p < 16; ++p) {
        int g = wv * 16 + p;
        int col = g * 4 + l4;
        int chs = l15 ^ (col & 7);
        const ushort* gb = BT + col * 128 + chs * 8;
        __builtin_amdgcn_global_load_lds(
            (const __attribute__((address_space(1))) void*)gb,
            (__attribute__((address_space(3))) void*)((char*)Bs + g * 1024), 16, 0, 0);
    }

    {
        int row = t >> 3, cp = (t & 7) * 2;
        int gr = rb + row; if (gr > M - 1) gr = M - 1;
        const float4* hp = (const float4*)(h + (size_t)gr * 128 + cp * 8);
        float4 v0 = hp[0], v1 = hp[1], v2 = hp[2], v3 = hp[3];
        uint4 u0, u1;
        u0.x = packbf(v0.x, v0.y); u0.y = packbf(v0.z, v0.w);
        u0.z = packbf(v1.x, v1.y); u0.w = packbf(v1.z, v1.w);
        u1.x = packbf(v2.x, v2.y); u1.y = packbf(v2.z, v2.w);
        u1.z = packbf(v3.x, v3.y); u1.w = packbf(v3.z, v3.w);
        *(uint4*)((char*)As + row * 256 + ((cp)     ^ (row & 7)) * 16) = u0;
        *(uint4*)((char*)As + row * 256 + ((cp + 1) ^ (row & 7)) * 16) = u1;
    }
    __syncthreads();

    f32x4 acc[4][4];
#pragma unroll
    for (int i = 0; i < 4; ++i)
#pragma unroll
        for (int j = 0; j < 4; ++j) acc[i][j] = (f32x4){0.f, 0.f, 0.f, 0.f};

    const char* Ab = (const char*)As;
    const char* Bb = (const char*)Bs;
#pragma unroll
    for (int ks = 0; ks < 4; ++ks) {
        bf16x8 a[4], b[4];
#pragma unroll
        for (int f = 0; f < 4; ++f) {
            int row = f * 16 + l15;
            int ch = (ks * 4 + l4) ^ (row & 7);
            a[f] = *(const bf16x8*)(Ab + row * 256 + ch * 16);
            int col = wv * 64 + f * 16 + l15;
            int ch2 = (ks * 4 + l4) ^ (col & 7);
            b[f] = *(const bf16x8*)(Bb + col * 256 + ch2 * 16);
        }
#pragma unroll
        for (int i = 0; i < 4; ++i)
#pragma unroll
            for (int j = 0; j < 4; ++j)
                acc[i][j] = __builtin_amdgcn_mfma_f32_16x16x32_bf16(a[i], b[j], acc[i][j], 0, 0, 0);
    }

    // ---- attention-dot epilogue (waves 0-3 cover x_r / x_i columns) ----
    if (wv < 4) {
        int var = wv >> 1;                       // 0 = reducible, 1 = irreducible
        const float* attS = var ? attsi : attsr;
        const float* attD = var ? attdi : attdr;
        float aS[4], aD[4];
#pragma unroll
        for (int j = 0; j < 4; ++j) {
            int c = (wv & 1) * 64 + j * 16 + l15;
            aS[j] = attS[c]; aD[j] = attD[c];
        }
#pragma unroll
        for (int i = 0; i < 4; ++i)
#pragma unroll
            for (int rr = 0; rr < 4; ++rr) {
                float ps = 0.f, pd = 0.f;
#pragma unroll
                for (int j = 0; j < 4; ++j) {
                    float v = acc[i][j][rr];
                    ps += v * aS[j]; pd += v * aD[j];
                }
#pragma unroll
                for (int d = 1; d < 16; d <<= 1) {
                    ps += __shfl_xor(ps, d); pd += __shfl_xor(pd, d);
                }
                if (l15 == 0) {
                    int row = i * 16 + l4 * 4 + rr;
                    atomicAdd(&dots[var * 2 + 0][row], ps);
                    atomicAdd(&dots[var * 2 + 1][row], pd);
                }
            }
    }

    // ---- C store ----
#pragma unroll
    for (int i = 0; i < 4; ++i) {
#pragma unroll
        for (int j = 0; j < 4; ++j) {
            int col = wv * 64 + j * 16 + l15;
#pragma unroll
            for (int r = 0; r < 4; ++r) {
                int gr = rb + i * 16 + l4 * 4 + r;
                if (gr < M) C[(size_t)gr * 512 + col] = f2bf(acc[i][j][r]);
            }
        }
    }

    __syncthreads();
    if (t < 256) {
        int arr = t >> 6, row = t & 63;
        int gr = rb + row;
        if (gr < M) {
            float v = dots[arr][row];
            if (arr == 0)      asr[gr] = v;
            else if (arr == 1) adr[gr] = v;
            else if (arr == 2) asi[gr] = v;
            else               adi[gr] = v;
        }
    }
}

// ---------------- two-level scan: A (per-block), B (block sums), C (fixup) ----------------
__global__ __launch_bounds__(256) void scanA_kernel(const int* __restrict__ cnt,
                                                    int* __restrict__ offv,
                                                    int* __restrict__ bsum, int n) {
    __shared__ int wsum[4];
    int t = threadIdx.x, lane = t & 63, wid = t >> 6;
    int i0 = blockIdx.x * 1024 + t * 4;
    int v[4];
#pragma unroll
    for (int j = 0; j < 4; ++j) { int i = i0 + j; v[j] = (i < n) ? cnt[i] : 0; }
    int s = v[0] + v[1] + v[2] + v[3];
    int incl = s;
#pragma unroll
    for (int d = 1; d < 64; d <<= 1) { int u = __shfl_up(incl, d); if (lane >= d) incl += u; }
    if (lane == 63) wsum[wid] = incl;
    __syncthreads();
    int wpre = 0;
    for (int w = 0; w < wid; ++w) wpre += wsum[w];
    int run = wpre + incl - s;
#pragma unroll
    for (int j = 0; j < 4; ++j) {
        int i = i0 + j;
        if (i < n) offv[i] = run;
        run += v[j];
    }
    if (t == 255) bsum[blockIdx.x] = wpre + incl;
}

__global__ void scanB_kernel(int* __restrict__ bsum, int* __restrict__ offv, int nb, int n) {
    int lane = threadIdx.x;   // 64 threads
    int carry = 0;
    for (int base = 0; base < nb; base += 64) {
        int i = base + lane;
        int v = (i < nb) ? bsum[i] : 0;
        int incl = v;
#pragma unroll
        for (int d = 1; d < 64; d <<= 1) { int u = __shfl_up(incl, d); if (lane >= d) incl += u; }
        if (i < nb) bsum[i] = carry + incl - v;
        carry += __shfl(incl, 63);
    }
    if (lane == 0) offv[n] = carry;
}

__global__ __launch_bounds__(256) void scanC_kernel(int* __restrict__ offv,
                                                    const int* __restrict__ bsum, int n) {
    int add = bsum[blockIdx.x];
    int i0 = blockIdx.x * 1024 + threadIdx.x * 4;
#pragma unroll
    for (int j = 0; j < 4; ++j) {
        int i = i0 + j;
        if (i < n) offv[i] += add;
    }
}

// ---------------- scatter: atomic-free 4B-record CSR permutation ----------------
__global__ __launch_bounds__(256) void scatter_kernel(
    const int* __restrict__ src, const int* __restrict__ dst,
    const int* __restrict__ rank, const uint* __restrict__ escal4,
    const void* __restrict__ red, const int* __restrict__ flags,
    const int* __restrict__ offv, uint* __restrict__ csr, int E) {
    int e = blockIdx.x * 256 + threadIdx.x;
    if (e >= E) return;
    int s = src[e], d = dst[e];
    uint ee = escal4[e];
    int notInt = flags[0], notFloat = flags[1];
    bool rr = redtest(red, d, notInt, notFloat);
    uint evb = rr ? (ee & 0xffffu) : (ee >> 16);
    csr[offv[d] + rank[e]] = (uint)s | (evb << 16);
}

// ---------------- node kernel: online softmax + 8-deep gather + residual + select + relu ----
__global__ __launch_bounds__(256) void node_kernel(
    const ushort* __restrict__ xcat,
    const float* __restrict__ adst_r, const float* __restrict__ adst_i,
    const float* __restrict__ asrc_r, const float* __restrict__ asrc_i,
    const void* __restrict__ red, const int* __restrict__ flags,
    const int* __restrict__ offv, const uint* __restrict__ csr,
    const float* __restrict__ bias_r, const float* __restrict__ bias_i,
    float* __restrict__ out, int n) {
    __shared__ uint2 buf[4][64];
    int wv = threadIdx.x >> 6, lane = threadIdx.x & 63;
    int node = blockIdx.x * 4 + wv;
    if (node >= n) return;

    int notInt = flags[0], notFloat = flags[1];
    bool r = redtest(red, node, notInt, notFloat);

    const float* asrc = r ? asrc_r : asrc_i;
    float adst = (r ? adst_r : adst_i)[node];
    uint vsel = r ? 0u : 256u;
    int b0 = offv[node], b1 = offv[node + 1];
    int k = b1 - b0;
    const char* xb = (const char*)xcat;
    uint lane4 = lane * 4;

    float m = -1e30f, denom = 0.f;
    float acc0a = 0.f, acc1a = 0.f, acc0b = 0.f, acc1b = 0.f;
    float sumE = 0.f;

    for (int base = b0; base < b1; base += 64) {
        int j = base + lane;
        float al = -1e30f; uint soff = 0;
        if (j < b1) {
            uint rec = csr[j];
            uint s = rec & 0xffffu;
            float ev = bfhi(rec);
            sumE += ev;
            soff = s * 1024u + vsel;
            float a = asrc[s] + ev + adst;
            al = (a >= 0.f) ? a : NEG_SLOPE * a;
        }
        float cm = al;
#pragma unroll
        for (int d = 32; d; d >>= 1) cm = fmaxf(cm, __shfl_xor(cm, d));
        float mn = fmaxf(m, cm);
        float sc = __expf(m - mn);
        denom *= sc; acc0a *= sc; acc1a *= sc; acc0b *= sc; acc1b *= sc;
        m = mn;
        float ex = (j < b1) ? __expf(al - mn) : 0.f;
        buf[wv][lane] = make_uint2(__float_as_uint(ex), soff);
        __builtin_amdgcn_wave_barrier();
        int cc = min(64, b1 - base);
        int ccp = (cc + 7) & ~7;
        for (int tq = 0; tq < ccp; tq += 8) {
            uint2 u[8];
#pragma unroll
            for (int q = 0; q < 8; ++q) u[q] = buf[wv][tq + q];
            uint v[8];
#pragma unroll
            for (int q = 0; q < 8; ++q) v[q] = *(const uint*)(xb + u[q].y + lane4);
#pragma unroll
            for (int q = 0; q < 4; ++q) {
                float w = __uint_as_float(u[q].x);
                acc0a += w * bflo(v[q]); acc1a += w * bfhi(v[q]);
            }
#pragma unroll
            for (int q = 4; q < 8; ++q) {
                float w = __uint_as_float(u[q].x);
                acc0b += w * bflo(v[q]); acc1b += w * bfhi(v[q]);
            }
        }
        float exs = ex;
#pragma unroll
        for (int d = 32; d; d >>= 1) exs += __shfl_xor(exs, d);
        denom += exs;
        __builtin_amdgcn_wave_barrier();
    }
    float acc0 = acc0a + acc0b, acc1 = acc1a + acc1b;

    // self loop
#pragma unroll
    for (int d = 32; d; d >>= 1) sumE += __shfl_xor(sumE, d);
    float eself = sumE / fmaxf((float)k, 1.f);
    float a = asrc[node] + adst + eself;
    float aself = (a >= 0.f) ? a : NEG_SLOPE * a;
    float mn = fmaxf(m, aself);
    float sc = __expf(m - mn);
    float exl = __expf(aself - mn);
    denom = denom * sc + exl;
    uint voff = (uint)node * 1024u + vsel;
    uint vsw = *(const uint*)(xb + voff + lane4);
    acc0 = acc0 * sc + exl * bflo(vsw);
    acc1 = acc1 * sc + exl * bfhi(vsw);

    float inv = 1.f / denom;
    uint roff = (uint)node * 1024u + (r ? 512u : 768u);
    uint bw = *(const uint*)(xb + roff + lane4);
    float2 bi2 = ((const float2*)(r ? bias_r : bias_i))[lane];
    float o0 = acc0 * inv + bflo(bw) + bi2.x;
    float o1 = acc1 * inv + bfhi(bw) + bi2.y;
    ((float2*)out)[(size_t)node * 64 + lane] = make_float2(fmaxf(o0, 0.f), fmaxf(o1, 0.f));
}

extern "C" void kernel_launch(void* const* d_in, const int* in_sizes, int n_in,
                              void* d_out, int out_size, void* d_ws, size_t ws_size,
                              hipStream_t stream) {
    const float* h          = (const float*)d_in[0];
    const int*   edge_index = (const int*)d_in[1];
    const float* edge_attr  = (const float*)d_in[2];
    const void*  reducible  = d_in[3];
    const float* red_W      = (const float*)d_in[4];
    const float* red_att_src= (const float*)d_in[5];
    const float* red_att_dst= (const float*)d_in[6];
    const float* red_W_edge = (const float*)d_in[7];
    const float* red_att_edge=(const float*)d_in[8];
    const float* red_W_res  = (const float*)d_in[9];
    const float* red_bias   = (const float*)d_in[10];
    const float* irr_W      = (const float*)d_in[11];
    const float* irr_att_src= (const float*)d_in[12];
    const float* irr_att_dst= (const float*)d_in[13];
    const float* irr_W_edge = (const float*)d_in[14];
    const float* irr_att_edge=(const float*)d_in[15];
    const float* irr_W_res  = (const float*)d_in[16];
    const float* irr_bias   = (const float*)d_in[17];

    const int N = in_sizes[0] / CDIM;
    const int E = in_sizes[1] / 2;
    const int* src = edge_index;
    const int* dst = edge_index + E;
    const int nb = (N + 1023) / 1024;

    float* out = (float*)d_out;

    size_t cur = 0;
    auto alloc = [&](size_t bytes) { size_t p = cur; cur = (cur + bytes + 255) & ~(size_t)255; return p; };
    char* ws = (char*)d_ws;
    size_t o_xcat  = alloc((size_t)N * 512 * 2);   // bf16 [x_r|x_i|res_r|res_i]
    size_t o_bcat  = alloc(512 * 128 * 2);
    size_t o_we    = alloc(256);
    size_t o_asr   = alloc((size_t)N * 4);
    size_t o_adr   = alloc((size_t)N * 4);
    size_t o_asi   = alloc((size_t)N * 4);
    size_t o_adi   = alloc((size_t)N * 4);
    size_t o_flags = alloc(256);
    size_t o_cnt   = alloc((size_t)N * 4);
    size_t o_off   = alloc((size_t)(N + 1) * 4);
    size_t o_bsum  = alloc((size_t)(nb + 1) * 4);
    size_t o_rank  = alloc((size_t)E * 4);
    size_t o_escal = alloc((size_t)E * 4);
    size_t o_csr   = alloc((size_t)E * 4);
    if (cur > ws_size) return;

    ushort* xcat = (ushort*)(ws + o_xcat);
    ushort* bcat = (ushort*)(ws + o_bcat);
    float* we    = (float*)(ws + o_we);
    float* asr   = (float*)(ws + o_asr);
    float* adr   = (float*)(ws + o_adr);
    float* asi   = (float*)(ws + o_asi);
    float* adi   = (float*)(ws + o_adi);
    int*   flags = (int*)(ws + o_flags);
    int*   cnt   = (int*)(ws + o_cnt);
    int*   offv  = (int*)(ws + o_off);
    int*   bsum  = (int*)(ws + o_bsum);
    int*   rank  = (int*)(ws + o_rank);
    uint*  escal4= (uint*)(ws + o_escal);
    uint*  csr   = (uint*)(ws + o_csr);

    hipMemsetAsync(flags, 0, 8, stream);
    hipMemsetAsync(cnt, 0, (size_t)N * 4, stream);

    bcatwe_kernel<<<257, 256, 0, stream>>>(red_W, irr_W, red_W_res, irr_W_res, bcat,
                                           red_W_edge, red_att_edge, irr_W_edge, irr_att_edge, we);

    int nwords = N / 4;
    prep_kernel<<<(E + 255) / 256, 256, 0, stream>>>((const uint*)reducible, nwords, flags,
                                                     dst, cnt, rank, edge_attr, we, escal4, E);

    gemm_fused<<<(N + 63) / 64, 512, 0, stream>>>(h, bcat, xcat,
                                                  red_att_src, red_att_dst,
                                                  irr_att_src, irr_att_dst,
                                                  asr, adr, asi, adi, N);

    scanA_kernel<<<nb, 256, 0, stream>>>(cnt, offv, bsum, N);
    scanB_kernel<<<1, 64, 0, stream>>>(bsum, offv, nb, N);
    scanC_kernel<<<nb, 256, 0, stream>>>(offv, bsum, N);

    scatter_kernel<<<(E + 255) / 256, 256, 0, stream>>>(src, dst, rank, escal4,
                                                        reducible, flags, offv, csr, E);

    node_kernel<<<(N + 3) / 4, 256, 0, stream>>>(xcat, adr, adi, asr, asi,
                                                 reducible, flags, offv, csr,
                                                 red_bias, irr_bias, out, N);
}

// Round 8
// 148.768 us; speedup vs baseline: 1.8911x; 1.0528x over previous
//
#include <hip/hip_runtime.h>
#include <hip/hip_bf16.h>

#define CDIM 128
#define EDIM 16
#define NEG_SLOPE 0.2f

typedef __attribute__((ext_vector_type(8))) short bf16x8;
typedef __attribute__((ext_vector_type(4))) float f32x4;
typedef unsigned int uint;
typedef unsigned short ushort;

__device__ __forceinline__ ushort f2bf(float f) {
    uint u = __float_as_uint(f);
    return (ushort)((u + 0x7fffu + ((u >> 16) & 1u)) >> 16);
}
__device__ __forceinline__ uint packbf(float lo, float hi) {
    return ((uint)f2bf(hi) << 16) | (uint)f2bf(lo);
}
__device__ __forceinline__ float bflo(uint w) { return __uint_as_float(w << 16); }
__device__ __forceinline__ float bfhi(uint w) { return __uint_as_float(w & 0xffff0000u); }

__device__ __forceinline__ bool redtest(const void* red, int i, int notInt, int notFloat) {
    if (!notInt)        return ((const int*)red)[i] != 0;
    else if (!notFloat) return ((const float*)red)[i] != 0.f;
    else                return ((const unsigned char*)red)[i] != 0;
}

// ---------------- BcatT[c][k] bf16 (transposed) + w_e scalars ----------------
__global__ void bcatwe_kernel(const float* __restrict__ Wr, const float* __restrict__ Wi,
                              const float* __restrict__ Wrr, const float* __restrict__ Wri,
                              ushort* __restrict__ BT,
                              const float* __restrict__ WeR, const float* __restrict__ aeR,
                              const float* __restrict__ WeI, const float* __restrict__ aeI,
                              float* __restrict__ we) {
    if (blockIdx.x < 256) {
        int idx = blockIdx.x * 256 + threadIdx.x;
        int c = idx >> 7, k = idx & 127;
        const float* srcm;
        if (c < 128)      srcm = Wr;
        else if (c < 256) srcm = Wi;
        else if (c < 384) srcm = Wrr;
        else              srcm = Wri;
        BT[idx] = f2bf(srcm[k * 128 + (c & 127)]);
    } else {
        int lane = threadIdx.x;
        if (lane < 16) {
            float s = 0.f;
            for (int c = 0; c < CDIM; ++c) s += WeR[lane * CDIM + c] * aeR[c];
            we[lane] = s;
        } else if (lane < 32) {
            int j = lane - 16;
            float s = 0.f;
            for (int c = 0; c < CDIM; ++c) s += WeI[j * CDIM + c] * aeI[c];
            we[16 + j] = s;
        }
    }
}

// ---------------- prep: flags + histogram(rank) + e-scalars + h->bf16 ----------------
__global__ __launch_bounds__(256) void prep_kernel(const uint* __restrict__ red, int nwords,
                                                   int* __restrict__ flags,
                                                   const int* __restrict__ dst, int* __restrict__ cnt,
                                                   int* __restrict__ rank,
                                                   const float* __restrict__ ea, const float* __restrict__ we,
                                                   uint* __restrict__ escal4,
                                                   const float* __restrict__ h, ushort* __restrict__ hbf,
                                                   int E, int n4) {
    int i = blockIdx.x * 256 + threadIdx.x;
    if (i < nwords) {
        uint w = red[i];
        bool isInt = (w <= 1u);
        bool isFloat = (w == 0u) || (w == 0x3f800000u);
        if (!isInt) atomicOr(&flags[0], 1);
        if (!isFloat) atomicOr(&flags[1], 1);
    }
    if (i < E) {
        rank[i] = atomicAdd(&cnt[dst[i]], 1);
        const float4* row = (const float4*)(ea + (size_t)i * EDIM);
        const float4* we4 = (const float4*)we;
        float er = 0.f, ei = 0.f;
#pragma unroll
        for (int q = 0; q < 4; ++q) {
            float4 v = row[q];
            float4 wr = we4[q], wi = we4[4 + q];
            er += v.x * wr.x + v.y * wr.y + v.z * wr.z + v.w * wr.w;
            ei += v.x * wi.x + v.y * wi.y + v.z * wi.z + v.w * wi.w;
        }
        escal4[i] = packbf(er, ei);   // lo=er, hi=ei
    }
    if (i < n4) {
        float4 v = ((const float4*)h)[i];
        ushort4 o;
        o.x = f2bf(v.x); o.y = f2bf(v.y); o.z = f2bf(v.z); o.w = f2bf(v.w);
        ((ushort4*)hbf)[i] = o;
    }
}

// ---------------- MFMA GEMM 128x128-tile + fused attention dots ----------------
// xcat[M][512](bf16) = hbf[M][128] @ Bcat. grid (ceil(M/128), 4); by=0 -> asr/adr, by=1 -> asi/adi.
__global__ __launch_bounds__(256) void gemm_dots(const ushort* __restrict__ A,
                                                 const ushort* __restrict__ BT,
                                                 ushort* __restrict__ C,
                                                 const float* __restrict__ attsr, const float* __restrict__ attdr,
                                                 const float* __restrict__ attsi, const float* __restrict__ attdi,
                                                 float* __restrict__ asr, float* __restrict__ adr,
                                                 float* __restrict__ asi, float* __restrict__ adi, int M) {
    __shared__ ushort As[128 * 128];   // 32 KiB
    __shared__ ushort Bs[128 * 128];   // 32 KiB
    __shared__ float dots[2][128];
    int t = threadIdx.x;
    int lane = t & 63, wv = t >> 6;
    int rb = blockIdx.x * 128, cb = blockIdx.y * 128;
    int by = blockIdx.y;

    if (t < 128) { dots[0][t] = 0.f; dots[1][t] = 0.f; }

    // stage A[128][128] and BT-slab[128][128] into LDS, pre-swizzled source chunk
    int rsub = wv * 4 + (lane >> 4);   // 0..15
    int c0 = lane & 15;
#pragma unroll
    for (int p = 0; p < 8; ++p) {
        int row = p * 16 + rsub;       // 0..127
        int chunk = c0 ^ (row & 7);
        int gra = rb + row; if (gra > M - 1) gra = M - 1;
        const ushort* ga = A + (size_t)gra * 128 + chunk * 8;
        __builtin_amdgcn_global_load_lds(
            (const __attribute__((address_space(1))) void*)ga,
            (__attribute__((address_space(3))) void*)((char*)As + p * 4096 + wv * 1024),
            16, 0, 0);
        const ushort* gb = BT + (size_t)(cb + row) * 128 + chunk * 8;
        __builtin_amdgcn_global_load_lds(
            (const __attribute__((address_space(1))) void*)gb,
            (__attribute__((address_space(3))) void*)((char*)Bs + p * 4096 + wv * 1024),
            16, 0, 0);
    }
    __syncthreads();

    int wr = wv >> 1, wc = wv & 1;
    int l15 = lane & 15, l4 = lane >> 4;
    f32x4 acc[4][4];
#pragma unroll
    for (int i = 0; i < 4; ++i)
#pragma unroll
        for (int j = 0; j < 4; ++j) acc[i][j] = (f32x4){0.f, 0.f, 0.f, 0.f};

    const char* Ab = (const char*)As;
    const char* Bb = (const char*)Bs;
#pragma unroll
    for (int ks = 0; ks < 4; ++ks) {
        bf16x8 a[4], b[4];
#pragma unroll
        for (int f = 0; f < 4; ++f) {
            int row = wr * 64 + f * 16 + l15;
            int ch = (ks * 4 + l4) ^ (row & 7);
            a[f] = *(const bf16x8*)(Ab + row * 256 + ch * 16);
            int col = wc * 64 + f * 16 + l15;
            int ch2 = (ks * 4 + l4) ^ (col & 7);
            b[f] = *(const bf16x8*)(Bb + col * 256 + ch2 * 16);
        }
#pragma unroll
        for (int i = 0; i < 4; ++i)
#pragma unroll
            for (int j = 0; j < 4; ++j)
                acc[i][j] = __builtin_amdgcn_mfma_f32_16x16x32_bf16(a[i], b[j], acc[i][j], 0, 0, 0);
    }

    // ---- attention-dot epilogue (by 0/1 only; block covers the full 128 cols of one variant)
    if (by < 2) {
        const float* attS = by ? attsi : attsr;
        const float* attD = by ? attdi : attdr;
        float aS[4], aD[4];
#pragma unroll
        for (int j = 0; j < 4; ++j) {
            int c = wc * 64 + j * 16 + l15;
            aS[j] = attS[c]; aD[j] = attD[c];
        }
#pragma unroll
        for (int i = 0; i < 4; ++i)
#pragma unroll
            for (int rr = 0; rr < 4; ++rr) {
                float ps = 0.f, pd = 0.f;
#pragma unroll
                for (int j = 0; j < 4; ++j) {
                    float v = acc[i][j][rr];
                    ps += v * aS[j]; pd += v * aD[j];
                }
#pragma unroll
                for (int d = 1; d < 16; d <<= 1) {
                    ps += __shfl_xor(ps, d); pd += __shfl_xor(pd, d);
                }
                if (l15 == 0) {
                    int row = wr * 64 + i * 16 + l4 * 4 + rr;
                    atomicAdd(&dots[0][row], ps);
                    atomicAdd(&dots[1][row], pd);
                }
            }
    }

    // ---- C store ----
#pragma unroll
    for (int i = 0; i < 4; ++i) {
        int rl = wr * 64 + i * 16 + l4 * 4;
#pragma unroll
        for (int j = 0; j < 4; ++j) {
            int col = cb + wc * 64 + j * 16 + l15;
#pragma unroll
            for (int r = 0; r < 4; ++r) {
                int gr = rb + rl + r;
                if (gr < M) C[(size_t)gr * 512 + col] = f2bf(acc[i][j][r]);
            }
        }
    }

    if (by < 2) {
        __syncthreads();
        if (t < 128) {
            int gr = rb + t;
            if (gr < M) {
                if (by == 0) { asr[gr] = dots[0][t]; adr[gr] = dots[1][t]; }
                else         { asi[gr] = dots[0][t]; adi[gr] = dots[1][t]; }
            }
        }
    }
}

// ---------------- two-level scan ----------------
__global__ __launch_bounds__(256) void scanA_kernel(const int* __restrict__ cnt,
                                                    int* __restrict__ offv,
                                                    int* __restrict__ bsum, int n) {
    __shared__ int wsum[4];
    int t = threadIdx.x, lane = t & 63, wid = t >> 6;
    int i0 = blockIdx.x * 1024 + t * 4;
    int v[4];
#pragma unroll
    for (int j = 0; j < 4; ++j) { int i = i0 + j; v[j] = (i < n) ? cnt[i] : 0; }
    int s = v[0] + v[1] + v[2] + v[3];
    int incl = s;
#pragma unroll
    for (int d = 1; d < 64; d <<= 1) { int u = __shfl_up(incl, d); if (lane >= d) incl += u; }
    if (lane == 63) wsum[wid] = incl;
    __syncthreads();
    int wpre = 0;
    for (int w = 0; w < wid; ++w) wpre += wsum[w];
    int run = wpre + incl - s;
#pragma unroll
    for (int j = 0; j < 4; ++j) {
        int i = i0 + j;
        if (i < n) offv[i] = run;
        run += v[j];
    }
    if (t == 255) bsum[blockIdx.x] = wpre + incl;
}

__global__ void scanB_kernel(int* __restrict__ bsum, int* __restrict__ offv, int nb, int n) {
    int lane = threadIdx.x;   // 64 threads
    int carry = 0;
    for (int base = 0; base < nb; base += 64) {
        int i = base + lane;
        int v = (i < nb) ? bsum[i] : 0;
        int incl = v;
#pragma unroll
        for (int d = 1; d < 64; d <<= 1) { int u = __shfl_up(incl, d); if (lane >= d) incl += u; }
        if (i < nb) bsum[i] = carry + incl - v;
        carry += __shfl(incl, 63);
    }
    if (lane == 0) offv[n] = carry;
}

__global__ __launch_bounds__(256) void scanC_kernel(int* __restrict__ offv,
                                                    const int* __restrict__ bsum, int n) {
    int add = bsum[blockIdx.x];
    int i0 = blockIdx.x * 1024 + threadIdx.x * 4;
#pragma unroll
    for (int j = 0; j < 4; ++j) {
        int i = i0 + j;
        if (i < n) offv[i] += add;
    }
}

// ---------------- scatter: atomic-free 4B-record CSR permutation ----------------
__global__ __launch_bounds__(256) void scatter_kernel(
    const int* __restrict__ src, const int* __restrict__ dst,
    const int* __restrict__ rank, const uint* __restrict__ escal4,
    const void* __restrict__ red, const int* __restrict__ flags,
    const int* __restrict__ offv, uint* __restrict__ csr, int E) {
    int e = blockIdx.x * 256 + threadIdx.x;
    if (e >= E) return;
    int s = src[e], d = dst[e];
    uint ee = escal4[e];
    int notInt = flags[0], notFloat = flags[1];
    bool rr = redtest(red, d, notInt, notFloat);
    uint evb = rr ? (ee & 0xffffu) : (ee >> 16);
    csr[offv[d] + rank[e]] = (uint)s | (evb << 16);
}

// ---------------- node kernel: online softmax + 8-deep gather + residual + select + relu ----
__global__ __launch_bounds__(256) void node_kernel(
    const ushort* __restrict__ xcat,
    const float* __restrict__ adst_r, const float* __restrict__ adst_i,
    const float* __restrict__ asrc_r, const float* __restrict__ asrc_i,
    const void* __restrict__ red, const int* __restrict__ flags,
    const int* __restrict__ offv, const uint* __restrict__ csr,
    const float* __restrict__ bias_r, const float* __restrict__ bias_i,
    float* __restrict__ out, int n) {
    __shared__ uint2 buf[4][64];
    int wv = threadIdx.x >> 6, lane = threadIdx.x & 63;
    int node = blockIdx.x * 4 + wv;
    if (node >= n) return;

    int notInt = flags[0], notFloat = flags[1];
    bool r = redtest(red, node, notInt, notFloat);

    const float* asrc = r ? asrc_r : asrc_i;
    float adst = (r ? adst_r : adst_i)[node];
    uint vsel = r ? 0u : 256u;
    int b0 = offv[node], b1 = offv[node + 1];
    int k = b1 - b0;
    const char* xb = (const char*)xcat;
    uint lane4 = lane * 4;

    float m = -1e30f, denom = 0.f;
    float acc0a = 0.f, acc1a = 0.f, acc0b = 0.f, acc1b = 0.f;
    float sumE = 0.f;

    for (int base = b0; base < b1; base += 64) {
        int j = base + lane;
        float al = -1e30f; uint soff = 0;
        if (j < b1) {
            uint rec = csr[j];
            uint s = rec & 0xffffu;
            float ev = bfhi(rec);
            sumE += ev;
            soff = s * 1024u + vsel;
            float a = asrc[s] + ev + adst;
            al = (a >= 0.f) ? a : NEG_SLOPE * a;
        }
        float cm = al;
#pragma unroll
        for (int d = 32; d; d >>= 1) cm = fmaxf(cm, __shfl_xor(cm, d));
        float mn = fmaxf(m, cm);
        float sc = __expf(m - mn);
        denom *= sc; acc0a *= sc; acc1a *= sc; acc0b *= sc; acc1b *= sc;
        m = mn;
        float ex = (j < b1) ? __expf(al - mn) : 0.f;
        buf[wv][lane] = make_uint2(__float_as_uint(ex), soff);
        __builtin_amdgcn_wave_barrier();
        int cc = min(64, b1 - base);
        int ccp = (cc + 7) & ~7;
        for (int tq = 0; tq < ccp; tq += 8) {
            uint2 u[8];
#pragma unroll
            for (int q = 0; q < 8; ++q) u[q] = buf[wv][tq + q];
            uint v[8];
#pragma unroll
            for (int q = 0; q < 8; ++q) v[q] = *(const uint*)(xb + u[q].y + lane4);
#pragma unroll
            for (int q = 0; q < 4; ++q) {
                float w = __uint_as_float(u[q].x);
                acc0a += w * bflo(v[q]); acc1a += w * bfhi(v[q]);
            }
#pragma unroll
            for (int q = 4; q < 8; ++q) {
                float w = __uint_as_float(u[q].x);
                acc0b += w * bflo(v[q]); acc1b += w * bfhi(v[q]);
            }
        }
        float exs = ex;
#pragma unroll
        for (int d = 32; d; d >>= 1) exs += __shfl_xor(exs, d);
        denom += exs;
        __builtin_amdgcn_wave_barrier();
    }
    float acc0 = acc0a + acc0b, acc1 = acc1a + acc1b;

    // self loop
#pragma unroll
    for (int d = 32; d; d >>= 1) sumE += __shfl_xor(sumE, d);
    float eself = sumE / fmaxf((float)k, 1.f);
    float a = asrc[node] + adst + eself;
    float aself = (a >= 0.f) ? a : NEG_SLOPE * a;
    float mn = fmaxf(m, aself);
    float sc = __expf(m - mn);
    float exl = __expf(aself - mn);
    denom = denom * sc + exl;
    uint voff = (uint)node * 1024u + vsel;
    uint vsw = *(const uint*)(xb + voff + lane4);
    acc0 = acc0 * sc + exl * bflo(vsw);
    acc1 = acc1 * sc + exl * bfhi(vsw);

    float inv = 1.f / denom;
    uint roff = (uint)node * 1024u + (r ? 512u : 768u);
    uint bw = *(const uint*)(xb + roff + lane4);
    float2 bi2 = ((const float2*)(r ? bias_r : bias_i))[lane];
    float o0 = acc0 * inv + bflo(bw) + bi2.x;
    float o1 = acc1 * inv + bfhi(bw) + bi2.y;
    ((float2*)out)[(size_t)node * 64 + lane] = make_float2(fmaxf(o0, 0.f), fmaxf(o1, 0.f));
}

extern "C" void kernel_launch(void* const* d_in, const int* in_sizes, int n_in,
                              void* d_out, int out_size, void* d_ws, size_t ws_size,
                              hipStream_t stream) {
    const float* h          = (const float*)d_in[0];
    const int*   edge_index = (const int*)d_in[1];
    const float* edge_attr  = (const float*)d_in[2];
    const void*  reducible  = d_in[3];
    const float* red_W      = (const float*)d_in[4];
    const float* red_att_src= (const float*)d_in[5];
    const float* red_att_dst= (const float*)d_in[6];
    const float* red_W_edge = (const float*)d_in[7];
    const float* red_att_edge=(const float*)d_in[8];
    const float* red_W_res  = (const float*)d_in[9];
    const float* red_bias   = (const float*)d_in[10];
    const float* irr_W      = (const float*)d_in[11];
    const float* irr_att_src= (const float*)d_in[12];
    const float* irr_att_dst= (const float*)d_in[13];
    const float* irr_W_edge = (const float*)d_in[14];
    const float* irr_att_edge=(const float*)d_in[15];
    const float* irr_W_res  = (const float*)d_in[16];
    const float* irr_bias   = (const float*)d_in[17];

    const int N = in_sizes[0] / CDIM;
    const int E = in_sizes[1] / 2;
    const int* src = edge_index;
    const int* dst = edge_index + E;
    const int nb = (N + 1023) / 1024;
    const int n4 = N * 128 / 4;

    float* out = (float*)d_out;

    size_t cur = 0;
    auto alloc = [&](size_t bytes) { size_t p = cur; cur = (cur + bytes + 255) & ~(size_t)255; return p; };
    char* ws = (char*)d_ws;
    size_t o_xcat  = alloc((size_t)N * 512 * 2);   // bf16 [x_r|x_i|res_r|res_i]
    size_t o_hbf   = alloc((size_t)N * 128 * 2);   // bf16 h
    size_t o_bcat  = alloc(512 * 128 * 2);
    size_t o_we    = alloc(256);
    size_t o_asr   = alloc((size_t)N * 4);
    size_t o_adr   = alloc((size_t)N * 4);
    size_t o_asi   = alloc((size_t)N * 4);
    size_t o_adi   = alloc((size_t)N * 4);
    size_t o_flags = alloc(256);
    size_t o_cnt   = alloc((size_t)N * 4);
    size_t o_off   = alloc((size_t)(N + 1) * 4);
    size_t o_bsum  = alloc((size_t)(nb + 1) * 4);
    size_t o_rank  = alloc((size_t)E * 4);
    size_t o_escal = alloc((size_t)E * 4);
    size_t o_csr   = alloc((size_t)E * 4);
    if (cur > ws_size) return;

    ushort* xcat = (ushort*)(ws + o_xcat);
    ushort* hbf  = (ushort*)(ws + o_hbf);
    ushort* bcat = (ushort*)(ws + o_bcat);
    float* we    = (float*)(ws + o_we);
    float* asr   = (float*)(ws + o_asr);
    float* adr   = (float*)(ws + o_adr);
    float* asi   = (float*)(ws + o_asi);
    float* adi   = (float*)(ws + o_adi);
    int*   flags = (int*)(ws + o_flags);
    int*   cnt   = (int*)(ws + o_cnt);
    int*   offv  = (int*)(ws + o_off);
    int*   bsum  = (int*)(ws + o_bsum);
    int*   rank  = (int*)(ws + o_rank);
    uint*  escal4= (uint*)(ws + o_escal);
    uint*  csr   = (uint*)(ws + o_csr);

    hipMemsetAsync(flags, 0, 8, stream);
    hipMemsetAsync(cnt, 0, (size_t)N * 4, stream);

    bcatwe_kernel<<<257, 256, 0, stream>>>(red_W, irr_W, red_W_res, irr_W_res, bcat,
                                           red_W_edge, red_att_edge, irr_W_edge, irr_att_edge, we);

    int nwords = N / 4;
    int pgrid = (max(E, n4) + 255) / 256;
    prep_kernel<<<pgrid, 256, 0, stream>>>((const uint*)reducible, nwords, flags,
                                           dst, cnt, rank, edge_attr, we, escal4,
                                           h, hbf, E, n4);

    dim3 ggrid((N + 127) / 128, 4);
    gemm_dots<<<ggrid, 256, 0, stream>>>(hbf, bcat, xcat,
                                         red_att_src, red_att_dst,
                                         irr_att_src, irr_att_dst,
                                         asr, adr, asi, adi, N);

    scanA_kernel<<<nb, 256, 0, stream>>>(cnt, offv, bsum, N);
    scanB_kernel<<<1, 64, 0, stream>>>(bsum, offv, nb, N);
    scanC_kernel<<<nb, 256, 0, stream>>>(offv, bsum, N);

    scatter_kernel<<<(E + 255) / 256, 256, 0, stream>>>(src, dst, rank, escal4,
                                                        reducible, flags, offv, csr, E);

    node_kernel<<<(N + 3) / 4, 256, 0, stream>>>(xcat, adr, adi, asr, asi,
                                                 reducible, flags, offv, csr,
                                                 red_bias, irr_bias, out, N);
}